// Round 11
// baseline (421.141 us; speedup 1.0000x reference)
//
#include <hip/hip_runtime.h>
#include <hip/hip_bf16.h>

// Problem constants
#define KN 2048
#define BB 4
#define DM 512
#define NH 8
#define HE 64
#define UP 40
#define NBH 32          // B*H
#define NROWS 8192      // KN*B
#define MiB(x) ((size_t)(x) << 20)

// ---------------------------------------------------------------------------
// Tiled f32 GEMM:  C[m,o] = (sum_k A[m,k]*W[o,k] + bias[o]) * scale
// tile 128x64, K-step 32, 256 threads, 8x4 register blocking.
// 1D grid of 512 with XCD-aware decode: xcd = bid&7 owns m-tiles xcd*8..+7
// for ALL o-tiles -> per-XCD L2 set = 2MB A + 1MB W (fits 4MB), A pulled once.
// ---------------------------------------------------------------------------
__global__ __launch_bounds__(256) void gemm_bt(
    const float* __restrict__ A, const float* __restrict__ W,
    const float* __restrict__ bias, float scale, float* __restrict__ C) {
  __shared__ float As[32][132];  // [k][m], padded
  __shared__ float Ws[32][68];   // [k][o]
  const int bid = blockIdx.x;
  const int mt = (bid & 7) * 8 + ((bid >> 3) & 7);  // 0..63
  const int ot = bid >> 6;                          // 0..7
  const int m0 = mt * 128;
  const int o0 = ot * 64;
  const int tid = threadIdx.x;
  const int tx = tid & 15;
  const int ty = tid >> 4;
  float acc[8][4] = {};

  for (int k0 = 0; k0 < 512; k0 += 32) {
#pragma unroll
    for (int i = 0; i < 4; ++i) {
      int flat = tid + i * 256;      // 0..1023
      int r = flat >> 3;             // 0..127
      int c4 = flat & 7;
      float4 av = *(const float4*)(A + (size_t)(m0 + r) * 512 + k0 + c4 * 4);
      As[c4 * 4 + 0][r] = av.x; As[c4 * 4 + 1][r] = av.y;
      As[c4 * 4 + 2][r] = av.z; As[c4 * 4 + 3][r] = av.w;
    }
#pragma unroll
    for (int i = 0; i < 2; ++i) {
      int flat = tid + i * 256;      // 0..511
      int r = flat >> 3;             // 0..63
      int c4 = flat & 7;
      float4 wv = *(const float4*)(W + (size_t)(o0 + r) * 512 + k0 + c4 * 4);
      Ws[c4 * 4 + 0][r] = wv.x; Ws[c4 * 4 + 1][r] = wv.y;
      Ws[c4 * 4 + 2][r] = wv.z; Ws[c4 * 4 + 3][r] = wv.w;
    }
    __syncthreads();
#pragma unroll
    for (int kk = 0; kk < 32; ++kk) {
      float a_[8], w_[4];
#pragma unroll
      for (int i = 0; i < 8; ++i) a_[i] = As[kk][ty * 8 + i];
#pragma unroll
      for (int j = 0; j < 4; ++j) w_[j] = Ws[kk][tx * 4 + j];
#pragma unroll
      for (int i = 0; i < 8; ++i)
#pragma unroll
        for (int j = 0; j < 4; ++j)
          acc[i][j] = fmaf(a_[i], w_[j], acc[i][j]);
    }
    __syncthreads();
  }

#pragma unroll
  for (int i = 0; i < 8; ++i) {
    int m = m0 + ty * 8 + i;
#pragma unroll
    for (int j = 0; j < 4; ++j) {
      int o = o0 + tx * 4 + j;
      C[(size_t)m * 512 + o] = (acc[i][j] + bias[o]) * scale;
    }
  }
}

// ---------------------------------------------------------------------------
// Transpose K into Kt[bh][e][n] for coalesced attention score reads.
// ---------------------------------------------------------------------------
__global__ __launch_bounds__(256) void transposeK_kernel(
    const float* __restrict__ K, float* __restrict__ Kt) {
  const int bh = blockIdx.x & 31;
  const int nt = blockIdx.x >> 5;       // 0..15
  const int b = bh >> 3, h = bh & 7;
  const int n0 = nt * 128;
  const int tid = threadIdx.x;
  __shared__ float T[128][65];

#pragma unroll
  for (int i = 0; i < 8; ++i) {
    int flat = tid + i * 256;           // 0..2047
    int r = flat >> 4;                  // 0..127
    int c4 = flat & 15;                 // 0..15
    float4 v = *(const float4*)(K + (((size_t)(n0 + r) * 4 + b) * 8 + h) * 64 + c4 * 4);
    T[r][c4 * 4 + 0] = v.x; T[r][c4 * 4 + 1] = v.y;
    T[r][c4 * 4 + 2] = v.z; T[r][c4 * 4 + 3] = v.w;
  }
  __syncthreads();

  const int nl = tid & 127;             // 0..127
  const int eg = tid >> 7;              // 0..1
#pragma unroll
  for (int e = eg * 32; e < eg * 32 + 32; ++e)
    Kt[((size_t)bh * 64 + e) * 2048 + n0 + nl] = T[nl][e];
}

// ---------------------------------------------------------------------------
// M scores, wave-cooperative gather. One wave per (bh, n). (R10 version)
// ---------------------------------------------------------------------------
__global__ __launch_bounds__(256) void mscore_kernel(
    const float* __restrict__ Q, const float* __restrict__ K,
    const int* __restrict__ idx, float* __restrict__ Mout) {
  const int bh = blockIdx.x & 31;
  const int c  = blockIdx.x >> 5;        // 0..511
  const int wv = threadIdx.x >> 6;       // 0..3
  const int lane = threadIdx.x & 63;
  const int n = c * 4 + wv;
  const int b = bh >> 3, h = bh & 7;
  const int g = lane >> 4;               // sample group 0..3
  const int e16 = lane & 15;             // element chunk within row

  const float4 qv = *(const float4*)(Q + (((size_t)n * 4 + b) * 8 + h) * 64 + e16 * 4);

  float mx = -INFINITY, sm = 0.f;
#pragma unroll
  for (int it = 0; it < 10; ++it) {
    const int s = it * 4 + g;
    const int kn = idx[n * UP + s];
    const float4 kv = *(const float4*)(K + (((size_t)kn * 4 + b) * 8 + h) * 64 + e16 * 4);
    float d = qv.x * kv.x + qv.y * kv.y + qv.z * kv.z + qv.w * kv.w;
    d += __shfl_xor(d, 1);
    d += __shfl_xor(d, 2);
    d += __shfl_xor(d, 4);
    d += __shfl_xor(d, 8);
    mx = fmaxf(mx, d);
    sm += d;
  }
  mx = fmaxf(mx, __shfl_xor(mx, 16));
  mx = fmaxf(mx, __shfl_xor(mx, 32));
  sm += __shfl_xor(sm, 16);
  sm += __shfl_xor(sm, 32);
  if (lane == 0) Mout[(size_t)bh * 2048 + n] = mx - sm * (1.0f / (float)KN);
}

// ---------------------------------------------------------------------------
// top-40 per (b,h): iterative argmax, lowest-index tiebreak
// ---------------------------------------------------------------------------
__global__ __launch_bounds__(256) void topk_kernel(
    const float* __restrict__ M, int* __restrict__ Mtop) {
  const int bh = blockIdx.x;
  __shared__ float vals[2048];
  __shared__ float rv[256];
  __shared__ int ri[256];
  const float* Mrow = M + (size_t)bh * 2048;
  for (int i = threadIdx.x; i < 2048; i += 256) vals[i] = Mrow[i];
  __syncthreads();
  for (int it = 0; it < UP; ++it) {
    float bv = -INFINITY; int bi = 0x7fffffff;
    for (int i = threadIdx.x; i < 2048; i += 256) {
      float v = vals[i];
      if (v > bv) { bv = v; bi = i; }
    }
    rv[threadIdx.x] = bv; ri[threadIdx.x] = bi;
    __syncthreads();
    for (int st = 128; st; st >>= 1) {
      if (threadIdx.x < st) {
        float ov = rv[threadIdx.x + st]; int oi = ri[threadIdx.x + st];
        float cv = rv[threadIdx.x];      int ci = ri[threadIdx.x];
        if (ov > cv || (ov == cv && oi < ci)) { rv[threadIdx.x] = ov; ri[threadIdx.x] = oi; }
      }
      __syncthreads();
    }
    if (threadIdx.x == 0) { Mtop[bh * UP + it] = ri[0]; vals[ri[0]] = -INFINITY; }
    __syncthreads();
  }
}

// ---------------------------------------------------------------------------
// mean of V: two-phase coalesced column-sum (V is a [2048][2048] matrix).
// ---------------------------------------------------------------------------
__global__ __launch_bounds__(256) void meanv_part(
    const float* __restrict__ V, float* __restrict__ part) {
  const int rc = blockIdx.x >> 3;      // 0..31
  const int cc = blockIdx.x & 7;       // 0..7
  const int c = cc * 256 + threadIdx.x;
  const float* p = V + (size_t)rc * 64 * 2048 + c;
  float acc = 0.f;
#pragma unroll 8
  for (int i = 0; i < 64; ++i) acc += p[(size_t)i * 2048];
  part[(size_t)rc * 2048 + c] = acc;
}

__global__ __launch_bounds__(256) void meanv_final(
    const float* __restrict__ part, float* __restrict__ mnV) {
  const int c = blockIdx.x * 256 + threadIdx.x;   // 8 blocks
  float acc = 0.f;
#pragma unroll
  for (int r = 0; r < 32; ++r) acc += part[(size_t)r * 2048 + c];
  mnV[c] = acc * (1.0f / (float)KN);
}

// ---------------------------------------------------------------------------
// Selected-row machinery for the sparse output GEMM.
// flags[b*2048+n] = 1 iff n selected for batch b by any head.
// ---------------------------------------------------------------------------
__global__ void selbuild_kernel(const int* __restrict__ Mtop,
                                int* __restrict__ flags) {
  const int i = blockIdx.x * 64 + threadIdx.x;   // 0..1279
  const int bh = i / UP;
  const int b = bh >> 3;
  flags[b * 2048 + Mtop[i]] = 1;
}

__global__ void selcompact_kernel(const int* __restrict__ flags,
                                  int* __restrict__ rows,
                                  int* __restrict__ cnt) {
  const int i = blockIdx.x * 256 + threadIdx.x;  // 0..8191
  if (flags[i]) {
    int p = atomicAdd(cnt, 1);
    rows[p] = i;                                  // flat row index b*2048+n
  }
}

// meanout[b][o] = dot(mnV[b*512..], Wo[o]) + bo[o]
__global__ __launch_bounds__(256) void meanout_kernel(
    const float* __restrict__ mnV, const float* __restrict__ Wo,
    const float* __restrict__ bo, float* __restrict__ mo) {
  const int b = blockIdx.x;           // 4 blocks
  for (int o = threadIdx.x; o < 512; o += 256) {
    const float* m = mnV + b * 512;
    const float* w = Wo + (size_t)o * 512;
    float acc = 0.f;
#pragma unroll 8
    for (int k = 0; k < 512; ++k) acc = fmaf(m[k], w[k], acc);
    mo[b * 512 + o] = acc + bo[o];
  }
}

// out[(b*2048+n)*512 + d] = mo[b*512 + d]  (broadcast fill, float4)
__global__ void fillout_kernel(const float* __restrict__ mo,
                               float* __restrict__ out) {
  size_t i = ((size_t)blockIdx.x * 256 + threadIdx.x) * 4;
  int d = (int)(i & 511);
  int b = (int)(i >> 20);
  float4 v = *(const float4*)(mo + (b << 9) + d);
  *(float4*)(out + i) = v;
}

// ---------------------------------------------------------------------------
// Sparse output GEMM over selected rows only (<=1280 of 8192).
// tile 64 rows x 64 outputs, 4x4 blocking; A rows gathered via rows[].
// ---------------------------------------------------------------------------
__global__ __launch_bounds__(256) void gemm_rows(
    const float* __restrict__ ctx, const float* __restrict__ W,
    const float* __restrict__ bias, const int* __restrict__ rows,
    const int* __restrict__ cnt, float* __restrict__ out) {
  __shared__ float As[32][68];
  __shared__ float Ws[32][68];
  __shared__ int rsel[64];
  const int rt = blockIdx.x >> 3;      // 0..19
  const int ot = blockIdx.x & 7;       // 0..7
  const int o0 = ot * 64;
  const int tid = threadIdx.x;
  const int tx = tid & 15;
  const int ty = tid >> 4;
  const int n = *cnt;

  if (rt * 64 >= n) return;            // whole tile out of range

  if (tid < 64) {
    int g = rt * 64 + tid;
    rsel[tid] = (g < n) ? rows[g] : rows[0];
  }
  __syncthreads();

  float acc[4][4] = {};
  for (int k0 = 0; k0 < 512; k0 += 32) {
#pragma unroll
    for (int i = 0; i < 2; ++i) {
      int flat = tid + i * 256;        // 0..511
      int r = flat >> 3;               // 0..63
      int c4 = flat & 7;
      float4 av = *(const float4*)(ctx + (size_t)rsel[r] * 512 + k0 + c4 * 4);
      float4 wv = *(const float4*)(W + (size_t)(o0 + r) * 512 + k0 + c4 * 4);
      As[c4 * 4 + 0][r] = av.x; As[c4 * 4 + 1][r] = av.y;
      As[c4 * 4 + 2][r] = av.z; As[c4 * 4 + 3][r] = av.w;
      Ws[c4 * 4 + 0][r] = wv.x; Ws[c4 * 4 + 1][r] = wv.y;
      Ws[c4 * 4 + 2][r] = wv.z; Ws[c4 * 4 + 3][r] = wv.w;
    }
    __syncthreads();
#pragma unroll
    for (int kk = 0; kk < 32; ++kk) {
      float a_[4], w_[4];
#pragma unroll
      for (int i = 0; i < 4; ++i) a_[i] = As[kk][ty * 4 + i];
#pragma unroll
      for (int j = 0; j < 4; ++j) w_[j] = Ws[kk][tx * 4 + j];
#pragma unroll
      for (int i = 0; i < 4; ++i)
#pragma unroll
        for (int j = 0; j < 4; ++j)
          acc[i][j] = fmaf(a_[i], w_[j], acc[i][j]);
    }
    __syncthreads();
  }

#pragma unroll
  for (int i = 0; i < 4; ++i) {
    int g = rt * 64 + ty * 4 + i;
    if (g < n) {
      int m = rsel[ty * 4 + i];
#pragma unroll
      for (int j = 0; j < 4; ++j) {
        int o = o0 + tx * 4 + j;
        out[(size_t)m * 512 + o] = acc[i][j] + bias[o];
      }
    }
  }
}

// ---------------------------------------------------------------------------
// Batched attention: one block per (bh, group of 5 queries), 256 blocks.
// ---------------------------------------------------------------------------
#define QG 5   // queries per block
__global__ __launch_bounds__(256) void attn_kernel(
    const float* __restrict__ Q, const float* __restrict__ Kt,
    const float* __restrict__ V, const int* __restrict__ Mtop,
    float* __restrict__ upd) {
  const int bh = blockIdx.x >> 3;
  const int g  = blockIdx.x & 7;        // query group
  const int b = bh >> 3, h = bh & 7;
  const int tid = threadIdx.x;
  const int wv = tid >> 6, lane = tid & 63;

  __shared__ float qs[QG][64];
  __shared__ float p[QG][2048];
  __shared__ float redm[QG][4];
  __shared__ float reds[QG][4];
  __shared__ float pvp[4][QG][64];

  for (int i = tid; i < QG * 64; i += 256) {
    int q = i >> 6, e = i & 63;
    int nq = Mtop[bh * UP + g * QG + q];
    qs[q][e] = Q[(((size_t)nq * 4 + b) * 8 + h) * 64 + e];
  }
  __syncthreads();

  const float* ktb = Kt + (size_t)bh * 64 * 2048;
  float sc[QG][8];
#pragma unroll
  for (int j = 0; j < 2; ++j) {
    const int nb = j * 1024 + tid * 4;
    float d[QG][4] = {};
    for (int e = 0; e < 64; ++e) {
      float4 kv = *(const float4*)(ktb + (size_t)e * 2048 + nb);
#pragma unroll
      for (int q = 0; q < QG; ++q) {
        float qe = qs[q][e];
        d[q][0] = fmaf(qe, kv.x, d[q][0]);
        d[q][1] = fmaf(qe, kv.y, d[q][1]);
        d[q][2] = fmaf(qe, kv.z, d[q][2]);
        d[q][3] = fmaf(qe, kv.w, d[q][3]);
      }
    }
#pragma unroll
    for (int q = 0; q < QG; ++q)
#pragma unroll
      for (int i = 0; i < 4; ++i) sc[q][j * 4 + i] = d[q][i];
  }

#pragma unroll
  for (int q = 0; q < QG; ++q) {
    float m_ = sc[q][0];
#pragma unroll
    for (int j = 1; j < 8; ++j) m_ = fmaxf(m_, sc[q][j]);
#pragma unroll
    for (int off = 1; off < 64; off <<= 1)
      m_ = fmaxf(m_, __shfl_xor(m_, off));
    if (lane == 0) redm[q][wv] = m_;
  }
  __syncthreads();
  float gmax[QG];
#pragma unroll
  for (int q = 0; q < QG; ++q)
    gmax[q] = fmaxf(fmaxf(redm[q][0], redm[q][1]),
                    fmaxf(redm[q][2], redm[q][3]));

  float lsum[QG] = {};
#pragma unroll
  for (int j = 0; j < 2; ++j) {
#pragma unroll
    for (int q = 0; q < QG; ++q) {
      float4 pe;
      pe.x = __expf(sc[q][j * 4 + 0] - gmax[q]);
      pe.y = __expf(sc[q][j * 4 + 1] - gmax[q]);
      pe.z = __expf(sc[q][j * 4 + 2] - gmax[q]);
      pe.w = __expf(sc[q][j * 4 + 3] - gmax[q]);
      *(float4*)(&p[q][j * 1024 + tid * 4]) = pe;
      lsum[q] += pe.x + pe.y + pe.z + pe.w;
    }
  }
#pragma unroll
  for (int q = 0; q < QG; ++q) {
    float s_ = lsum[q];
#pragma unroll
    for (int off = 1; off < 64; off <<= 1)
      s_ += __shfl_xor(s_, off);
    if (lane == 0) reds[q][wv] = s_;
  }
  __syncthreads();
  float denom[QG];
#pragma unroll
  for (int q = 0; q < QG; ++q)
    denom[q] = reds[q][0] + reds[q][1] + reds[q][2] + reds[q][3];

  float acc[QG] = {};
  for (int n = wv * 512; n < wv * 512 + 512; ++n) {
    float v = V[(((size_t)n * 4 + b) * 8 + h) * 64 + lane];
#pragma unroll
    for (int q = 0; q < QG; ++q) acc[q] = fmaf(p[q][n], v, acc[q]);
  }
#pragma unroll
  for (int q = 0; q < QG; ++q) pvp[wv][q][lane] = acc[q];
  __syncthreads();

  for (int i = tid; i < QG * 64; i += 256) {
    int q = i >> 6, e = i & 63;
    float r = (pvp[0][q][e] + pvp[1][q][e] + pvp[2][q][e] + pvp[3][q][e]) /
              denom[q];
    upd[(size_t)(bh * UP + g * QG + q) * 64 + e] = r;
  }
}

// ---------------------------------------------------------------------------
// ctx fill + scatter (ctx only needed for selected rows, but fill is cheap)
// ---------------------------------------------------------------------------
__global__ void fillctx_kernel(const float* __restrict__ meanV,
                               float* __restrict__ ctx) {
  size_t i = ((size_t)blockIdx.x * 256 + threadIdx.x) * 4;
  int d = (int)(i & 511);
  int b = (int)(i >> 20);
  float4 v = *(const float4*)(meanV + (b << 9) + d);
  *(float4*)(ctx + i) = v;
}

__global__ void scatter_kernel(const float* __restrict__ upd,
                               const int* __restrict__ Mtop,
                               float* __restrict__ ctx) {
  const int blk = blockIdx.x;   // bh*40 + s
  const int bh = blk / UP;
  const int b = bh >> 3, h = bh & 7;
  const int n = Mtop[blk];
  ctx[((size_t)(b * 2048 + n)) * 512 + h * 64 + threadIdx.x] =
      upd[(size_t)blk * 64 + threadIdx.x];
}

// ---------------------------------------------------------------------------
// Workspace layout (65 MiB used; ws >= 113 MiB proven in R4):
//   [0,       256K)    Mbuf   32*2048 f32
//   [256K,    576K)    upd    1280*64 f32
//   [589824,  598016)  mnV    32*64 f32
//   [598016,  603136)  Mtop   1280 i32
//   [634880,  897024)  vpart  32*2048 f32
//   [903168,  935936)  flags  8192 i32
//   [935936,  935940)  cnt    1 i32
//   [936192,  941312)  rows   1280 i32
//   [941312,  949504)  mo     4*512 f32
//   [1M, 17M) Q (ctx alias)   [17M, 33M) K   [33M, 49M) V   [49M, 65M) Kt
// ---------------------------------------------------------------------------
extern "C" void kernel_launch(void* const* d_in, const int* in_sizes, int n_in,
                              void* d_out, int out_size, void* d_ws,
                              size_t ws_size, hipStream_t stream) {
  const float* query = (const float*)d_in[0];
  const float* key   = (const float*)d_in[1];
  const float* value = (const float*)d_in[2];
  const int*   idxs  = (const int*)d_in[3];
  const float* Wq = (const float*)d_in[4];
  const float* bq = (const float*)d_in[5];
  const float* Wk = (const float*)d_in[6];
  const float* bk = (const float*)d_in[7];
  const float* Wv = (const float*)d_in[8];
  const float* bv = (const float*)d_in[9];
  const float* Wo = (const float*)d_in[10];
  const float* bo = (const float*)d_in[11];
  float* out = (float*)d_out;    // reference output dtype is float32

  char* ws = (char*)d_ws;
  float* Mbuf  = (float*)(ws + 0);
  float* upd   = (float*)(ws + 262144);
  float* mnV   = (float*)(ws + 589824);
  int*   Mtop  = (int*)  (ws + 598016);
  float* vpart = (float*)(ws + 634880);
  int*   flags = (int*)  (ws + 903168);
  int*   cnt   = (int*)  (ws + 935936);
  int*   rows  = (int*)  (ws + 936192);
  float* mo    = (float*)(ws + 941312);
  float* Q     = (float*)(ws + MiB(1));
  float* K     = (float*)(ws + MiB(17));
  float* V     = (float*)(ws + MiB(33));
  float* Kt    = (float*)(ws + MiB(49));
  float* ctx   = Q;   // Q dead after attn_kernel; ctx written afterwards

  // zero flags + cnt (contiguous region)
  hipMemsetAsync(flags, 0, 32768 + 4, stream);

  gemm_bt<<<512, 256, 0, stream>>>(query, Wq, bq, 0.125f, Q);
  gemm_bt<<<512, 256, 0, stream>>>(key,   Wk, bk, 1.0f,   K);
  gemm_bt<<<512, 256, 0, stream>>>(value, Wv, bv, 1.0f,   V);

  transposeK_kernel<<<512, 256, 0, stream>>>(K, Kt);

  mscore_kernel<<<16384, 256, 0, stream>>>(Q, K, idxs, Mbuf);
  topk_kernel<<<NBH, 256, 0, stream>>>(Mbuf, Mtop);
  selbuild_kernel<<<20, 64, 0, stream>>>(Mtop, flags);
  selcompact_kernel<<<32, 256, 0, stream>>>(flags, rows, cnt);

  meanv_part<<<256, 256, 0, stream>>>(V, vpart);
  meanv_final<<<8, 256, 0, stream>>>(vpart, mnV);
  attn_kernel<<<NBH * 8, 256, 0, stream>>>(Q, Kt, V, Mtop, upd);

  fillctx_kernel<<<4096, 256, 0, stream>>>(mnV, ctx);
  scatter_kernel<<<NBH * UP, 64, 0, stream>>>(upd, Mtop, ctx);

  meanout_kernel<<<4, 256, 0, stream>>>(mnV, Wo, bo, mo);
  fillout_kernel<<<4096, 256, 0, stream>>>(mo, out);
  gemm_rows<<<160, 256, 0, stream>>>(ctx, Wo, bo, rows, cnt, out);
}

// Round 12
// 377.760 us; speedup vs baseline: 1.1148x; 1.1148x over previous
//
#include <hip/hip_runtime.h>
#include <hip/hip_bf16.h>

// Problem constants
#define KN 2048
#define BB 4
#define DM 512
#define NH 8
#define HE 64
#define UP 40
#define NBH 32          // B*H
#define NROWS 8192      // KN*B
#define MiB(x) ((size_t)(x) << 20)

typedef __attribute__((ext_vector_type(8))) short short8;
typedef __attribute__((ext_vector_type(4))) float f32x4;

// bf16 split helpers (RNE)
__device__ __forceinline__ ushort f2bf(float x) {
  unsigned u = __float_as_uint(x);
  unsigned r = (u + 0x7FFFu + ((u >> 16) & 1u)) >> 16;
  return (ushort)r;
}
__device__ __forceinline__ float bf2f(ushort h) {
  return __uint_as_float((unsigned)h << 16);
}

// ---------------------------------------------------------------------------
// Split W (512x512 f32, row-major) into hi/lo bf16 planes (row-major ushort).
// ---------------------------------------------------------------------------
__global__ __launch_bounds__(256) void wsplit_kernel(
    const float* __restrict__ W, ushort* __restrict__ Wh,
    ushort* __restrict__ Wl) {
  int i = (blockIdx.x * 256 + threadIdx.x) * 2;   // 512 blocks -> 262144 elems
  float2 v = *(const float2*)(W + i);
  ushort h0 = f2bf(v.x), h1 = f2bf(v.y);
  ushort l0 = f2bf(v.x - bf2f(h0)), l1 = f2bf(v.y - bf2f(h1));
  *(ushort2*)(Wh + i) = make_ushort2(h0, h1);
  *(ushort2*)(Wl + i) = make_ushort2(l0, l1);
}

// ---------------------------------------------------------------------------
// Split-bf16 MFMA GEMM: C[m,o] = (sum_k A[m,k]*W[o,k] + bias[o]) * scale
// 4-term split (AhWh+AhWl+AlWh+AlWl) -> f32-class accuracy (selection-safe).
// Tile 128x64, 512 blocks (XCD-aware decode, FETCH proven 12MB in R11),
// 256 thr = 4 waves; wave w owns rows [w*32,w*32+32) x all 64 cols.
// A staged in LDS as bf16 h/l [128][32]; W fragments read from global bf16
// (L2-resident) -> no B-side LDS traffic. MFMA 16x16x32_bf16:
//   A-frag: lane holds A[lane%16][ (lane/16)*8 + i ]  (bf16x8 contiguous in K)
//   C/D   : col = lane&15, row = (lane>>4)*4 + reg    (m89-verified)
// ---------------------------------------------------------------------------
__global__ __launch_bounds__(256) void gemm_mfma(
    const float* __restrict__ A, const ushort* __restrict__ Wh,
    const ushort* __restrict__ Wl, const float* __restrict__ bias,
    float scale, float* __restrict__ C) {
  __shared__ ushort AsH[128][32];
  __shared__ ushort AsL[128][32];
  const int bid = blockIdx.x;
  const int mt = (bid & 7) * 8 + ((bid >> 3) & 7);  // 0..63
  const int ot = bid >> 6;                          // 0..7
  const int m0 = mt * 128, o0 = ot * 64;
  const int tid = threadIdx.x;
  const int w = tid >> 6, lane = tid & 63;
  const int fr = lane & 15;      // fragment row (A row / W row / C col)
  const int kc = lane >> 4;      // k-chunk (8 bf16)

  f32x4 acc[2][4];
#pragma unroll
  for (int i = 0; i < 2; ++i)
#pragma unroll
    for (int j = 0; j < 4; ++j)
#pragma unroll
      for (int r = 0; r < 4; ++r) acc[i][j][r] = 0.f;

  for (int k0 = 0; k0 < 512; k0 += 32) {
    // stage A tile 128x32 f32 -> bf16 h/l; 1024 float4 / 256 thr = 4 each
#pragma unroll
    for (int i = 0; i < 4; ++i) {
      int flat = tid + i * 256;        // 0..1023
      int r = flat >> 3, c4 = flat & 7;
      float4 av = *(const float4*)(A + (size_t)(m0 + r) * 512 + k0 + c4 * 4);
      ushort h0 = f2bf(av.x), h1 = f2bf(av.y), h2 = f2bf(av.z), h3 = f2bf(av.w);
      ushort l0 = f2bf(av.x - bf2f(h0)), l1 = f2bf(av.y - bf2f(h1));
      ushort l2 = f2bf(av.z - bf2f(h2)), l3 = f2bf(av.w - bf2f(h3));
      *(ushort4*)(&AsH[r][c4 * 4]) = make_ushort4(h0, h1, h2, h3);
      *(ushort4*)(&AsL[r][c4 * 4]) = make_ushort4(l0, l1, l2, l3);
    }
    __syncthreads();

    short8 ah[2], al[2], bh[4], bl[4];
#pragma unroll
    for (int i = 0; i < 2; ++i) {
      ah[i] = *(const short8*)(&AsH[w * 32 + i * 16 + fr][kc * 8]);
      al[i] = *(const short8*)(&AsL[w * 32 + i * 16 + fr][kc * 8]);
    }
#pragma unroll
    for (int j = 0; j < 4; ++j) {
      size_t off = (size_t)(o0 + j * 16 + fr) * 512 + k0 + kc * 8;
      bh[j] = *(const short8*)(Wh + off);
      bl[j] = *(const short8*)(Wl + off);
    }
#pragma unroll
    for (int i = 0; i < 2; ++i)
#pragma unroll
      for (int j = 0; j < 4; ++j) {
        acc[i][j] = __builtin_amdgcn_mfma_f32_16x16x32_bf16(ah[i], bh[j], acc[i][j], 0, 0, 0);
        acc[i][j] = __builtin_amdgcn_mfma_f32_16x16x32_bf16(ah[i], bl[j], acc[i][j], 0, 0, 0);
        acc[i][j] = __builtin_amdgcn_mfma_f32_16x16x32_bf16(al[i], bh[j], acc[i][j], 0, 0, 0);
        acc[i][j] = __builtin_amdgcn_mfma_f32_16x16x32_bf16(al[i], bl[j], acc[i][j], 0, 0, 0);
      }
    __syncthreads();
  }

#pragma unroll
  for (int i = 0; i < 2; ++i)
#pragma unroll
    for (int j = 0; j < 4; ++j)
#pragma unroll
      for (int r = 0; r < 4; ++r) {
        int m = m0 + w * 32 + i * 16 + (lane >> 4) * 4 + r;
        int o = o0 + j * 16 + fr;
        C[(size_t)m * 512 + o] = (acc[i][j][r] + bias[o]) * scale;
      }
}

// ---------------------------------------------------------------------------
// Transpose K into Kt[bh][e][n] for coalesced attention score reads.
// ---------------------------------------------------------------------------
__global__ __launch_bounds__(256) void transposeK_kernel(
    const float* __restrict__ K, float* __restrict__ Kt) {
  const int bh = blockIdx.x & 31;
  const int nt = blockIdx.x >> 5;       // 0..15
  const int b = bh >> 3, h = bh & 7;
  const int n0 = nt * 128;
  const int tid = threadIdx.x;
  __shared__ float T[128][65];

#pragma unroll
  for (int i = 0; i < 8; ++i) {
    int flat = tid + i * 256;           // 0..2047
    int r = flat >> 4;                  // 0..127
    int c4 = flat & 15;                 // 0..15
    float4 v = *(const float4*)(K + (((size_t)(n0 + r) * 4 + b) * 8 + h) * 64 + c4 * 4);
    T[r][c4 * 4 + 0] = v.x; T[r][c4 * 4 + 1] = v.y;
    T[r][c4 * 4 + 2] = v.z; T[r][c4 * 4 + 3] = v.w;
  }
  __syncthreads();

  const int nl = tid & 127;             // 0..127
  const int eg = tid >> 7;              // 0..1
#pragma unroll
  for (int e = eg * 32; e < eg * 32 + 32; ++e)
    Kt[((size_t)bh * 64 + e) * 2048 + n0 + nl] = T[nl][e];
}

// ---------------------------------------------------------------------------
// M scores, wave-cooperative gather. One wave per (bh, n).
// ---------------------------------------------------------------------------
__global__ __launch_bounds__(256) void mscore_kernel(
    const float* __restrict__ Q, const float* __restrict__ K,
    const int* __restrict__ idx, float* __restrict__ Mout) {
  const int bh = blockIdx.x & 31;
  const int c  = blockIdx.x >> 5;        // 0..511
  const int wv = threadIdx.x >> 6;       // 0..3
  const int lane = threadIdx.x & 63;
  const int n = c * 4 + wv;
  const int b = bh >> 3, h = bh & 7;
  const int g = lane >> 4;               // sample group 0..3
  const int e16 = lane & 15;             // element chunk within row

  const float4 qv = *(const float4*)(Q + (((size_t)n * 4 + b) * 8 + h) * 64 + e16 * 4);

  float mx = -INFINITY, sm = 0.f;
#pragma unroll
  for (int it = 0; it < 10; ++it) {
    const int s = it * 4 + g;
    const int kn = idx[n * UP + s];
    const float4 kv = *(const float4*)(K + (((size_t)kn * 4 + b) * 8 + h) * 64 + e16 * 4);
    float d = qv.x * kv.x + qv.y * kv.y + qv.z * kv.z + qv.w * kv.w;
    d += __shfl_xor(d, 1);
    d += __shfl_xor(d, 2);
    d += __shfl_xor(d, 4);
    d += __shfl_xor(d, 8);
    mx = fmaxf(mx, d);
    sm += d;
  }
  mx = fmaxf(mx, __shfl_xor(mx, 16));
  mx = fmaxf(mx, __shfl_xor(mx, 32));
  sm += __shfl_xor(sm, 16);
  sm += __shfl_xor(sm, 32);
  if (lane == 0) Mout[(size_t)bh * 2048 + n] = mx - sm * (1.0f / (float)KN);
}

// ---------------------------------------------------------------------------
// top-40 per (b,h): iterative argmax, lowest-index tiebreak
// ---------------------------------------------------------------------------
__global__ __launch_bounds__(256) void topk_kernel(
    const float* __restrict__ M, int* __restrict__ Mtop) {
  const int bh = blockIdx.x;
  __shared__ float vals[2048];
  __shared__ float rv[256];
  __shared__ int ri[256];
  const float* Mrow = M + (size_t)bh * 2048;
  for (int i = threadIdx.x; i < 2048; i += 256) vals[i] = Mrow[i];
  __syncthreads();
  for (int it = 0; it < UP; ++it) {
    float bv = -INFINITY; int bi = 0x7fffffff;
    for (int i = threadIdx.x; i < 2048; i += 256) {
      float v = vals[i];
      if (v > bv) { bv = v; bi = i; }
    }
    rv[threadIdx.x] = bv; ri[threadIdx.x] = bi;
    __syncthreads();
    for (int st = 128; st; st >>= 1) {
      if (threadIdx.x < st) {
        float ov = rv[threadIdx.x + st]; int oi = ri[threadIdx.x + st];
        float cv = rv[threadIdx.x];      int ci = ri[threadIdx.x];
        if (ov > cv || (ov == cv && oi < ci)) { rv[threadIdx.x] = ov; ri[threadIdx.x] = oi; }
      }
      __syncthreads();
    }
    if (threadIdx.x == 0) { Mtop[bh * UP + it] = ri[0]; vals[ri[0]] = -INFINITY; }
    __syncthreads();
  }
}

// ---------------------------------------------------------------------------
// mean of V: two-phase coalesced column-sum (V is a [2048][2048] matrix).
// ---------------------------------------------------------------------------
__global__ __launch_bounds__(256) void meanv_part(
    const float* __restrict__ V, float* __restrict__ part) {
  const int rc = blockIdx.x >> 3;      // 0..31
  const int cc = blockIdx.x & 7;       // 0..7
  const int c = cc * 256 + threadIdx.x;
  const float* p = V + (size_t)rc * 64 * 2048 + c;
  float acc = 0.f;
#pragma unroll 8
  for (int i = 0; i < 64; ++i) acc += p[(size_t)i * 2048];
  part[(size_t)rc * 2048 + c] = acc;
}

__global__ __launch_bounds__(256) void meanv_final(
    const float* __restrict__ part, float* __restrict__ mnV) {
  const int c = blockIdx.x * 256 + threadIdx.x;   // 8 blocks
  float acc = 0.f;
#pragma unroll
  for (int r = 0; r < 32; ++r) acc += part[(size_t)r * 2048 + c];
  mnV[c] = acc * (1.0f / (float)KN);
}

// ---------------------------------------------------------------------------
// Selected-row machinery for the sparse output GEMM.
// ---------------------------------------------------------------------------
__global__ void selbuild_kernel(const int* __restrict__ Mtop,
                                int* __restrict__ flags) {
  const int i = blockIdx.x * 64 + threadIdx.x;   // 0..1279
  const int bh = i / UP;
  const int b = bh >> 3;
  flags[b * 2048 + Mtop[i]] = 1;
}

__global__ void selcompact_kernel(const int* __restrict__ flags,
                                  int* __restrict__ rows,
                                  int* __restrict__ cnt) {
  const int i = blockIdx.x * 256 + threadIdx.x;  // 0..8191
  if (flags[i]) {
    int p = atomicAdd(cnt, 1);
    rows[p] = i;                                  // flat row index b*2048+n
  }
}

// meanout[b][o] = dot(mnV[b*512..], Wo[o]) + bo[o]
__global__ __launch_bounds__(256) void meanout_kernel(
    const float* __restrict__ mnV, const float* __restrict__ Wo,
    const float* __restrict__ bo, float* __restrict__ mo) {
  const int b = blockIdx.x;           // 4 blocks
  for (int o = threadIdx.x; o < 512; o += 256) {
    const float* m = mnV + b * 512;
    const float* w = Wo + (size_t)o * 512;
    float acc = 0.f;
#pragma unroll 8
    for (int k = 0; k < 512; ++k) acc = fmaf(m[k], w[k], acc);
    mo[b * 512 + o] = acc + bo[o];
  }
}

// out[(b*2048+n)*512 + d] = mo[b*512 + d]  (broadcast fill, float4)
__global__ void fillout_kernel(const float* __restrict__ mo,
                               float* __restrict__ out) {
  size_t i = ((size_t)blockIdx.x * 256 + threadIdx.x) * 4;
  int d = (int)(i & 511);
  int b = (int)(i >> 20);
  float4 v = *(const float4*)(mo + (b << 9) + d);
  *(float4*)(out + i) = v;
}

// ---------------------------------------------------------------------------
// Sparse output GEMM over selected rows only (<=1280 of 8192).
// ---------------------------------------------------------------------------
__global__ __launch_bounds__(256) void gemm_rows(
    const float* __restrict__ ctx, const float* __restrict__ W,
    const float* __restrict__ bias, const int* __restrict__ rows,
    const int* __restrict__ cnt, float* __restrict__ out) {
  __shared__ float As[32][68];
  __shared__ float Ws[32][68];
  __shared__ int rsel[64];
  const int rt = blockIdx.x >> 3;      // 0..19
  const int ot = blockIdx.x & 7;       // 0..7
  const int o0 = ot * 64;
  const int tid = threadIdx.x;
  const int tx = tid & 15;
  const int ty = tid >> 4;
  const int n = *cnt;

  if (rt * 64 >= n) return;            // whole tile out of range

  if (tid < 64) {
    int g = rt * 64 + tid;
    rsel[tid] = (g < n) ? rows[g] : rows[0];
  }
  __syncthreads();

  float acc[4][4] = {};
  for (int k0 = 0; k0 < 512; k0 += 32) {
#pragma unroll
    for (int i = 0; i < 2; ++i) {
      int flat = tid + i * 256;        // 0..511
      int r = flat >> 3;               // 0..63
      int c4 = flat & 7;
      float4 av = *(const float4*)(ctx + (size_t)rsel[r] * 512 + k0 + c4 * 4);
      float4 wv = *(const float4*)(W + (size_t)(o0 + r) * 512 + k0 + c4 * 4);
      As[c4 * 4 + 0][r] = av.x; As[c4 * 4 + 1][r] = av.y;
      As[c4 * 4 + 2][r] = av.z; As[c4 * 4 + 3][r] = av.w;
      Ws[c4 * 4 + 0][r] = wv.x; Ws[c4 * 4 + 1][r] = wv.y;
      Ws[c4 * 4 + 2][r] = wv.z; Ws[c4 * 4 + 3][r] = wv.w;
    }
    __syncthreads();
#pragma unroll
    for (int kk = 0; kk < 32; ++kk) {
      float a_[4], w_[4];
#pragma unroll
      for (int i = 0; i < 4; ++i) a_[i] = As[kk][ty * 4 + i];
#pragma unroll
      for (int j = 0; j < 4; ++j) w_[j] = Ws[kk][tx * 4 + j];
#pragma unroll
      for (int i = 0; i < 4; ++i)
#pragma unroll
        for (int j = 0; j < 4; ++j)
          acc[i][j] = fmaf(a_[i], w_[j], acc[i][j]);
    }
    __syncthreads();
  }

#pragma unroll
  for (int i = 0; i < 4; ++i) {
    int g = rt * 64 + ty * 4 + i;
    if (g < n) {
      int m = rsel[ty * 4 + i];
#pragma unroll
      for (int j = 0; j < 4; ++j) {
        int o = o0 + tx * 4 + j;
        out[(size_t)m * 512 + o] = acc[i][j] + bias[o];
      }
    }
  }
}

// ---------------------------------------------------------------------------
// Batched attention: one block per (bh, group of 5 queries), 256 blocks.
// ---------------------------------------------------------------------------
#define QG 5   // queries per block
__global__ __launch_bounds__(256) void attn_kernel(
    const float* __restrict__ Q, const float* __restrict__ Kt,
    const float* __restrict__ V, const int* __restrict__ Mtop,
    float* __restrict__ upd) {
  const int bh = blockIdx.x >> 3;
  const int g  = blockIdx.x & 7;        // query group
  const int b = bh >> 3, h = bh & 7;
  const int tid = threadIdx.x;
  const int wv = tid >> 6, lane = tid & 63;

  __shared__ float qs[QG][64];
  __shared__ float p[QG][2048];
  __shared__ float redm[QG][4];
  __shared__ float reds[QG][4];
  __shared__ float pvp[4][QG][64];

  for (int i = tid; i < QG * 64; i += 256) {
    int q = i >> 6, e = i & 63;
    int nq = Mtop[bh * UP + g * QG + q];
    qs[q][e] = Q[(((size_t)nq * 4 + b) * 8 + h) * 64 + e];
  }
  __syncthreads();

  const float* ktb = Kt + (size_t)bh * 64 * 2048;
  float sc[QG][8];
#pragma unroll
  for (int j = 0; j < 2; ++j) {
    const int nb = j * 1024 + tid * 4;
    float d[QG][4] = {};
    for (int e = 0; e < 64; ++e) {
      float4 kv = *(const float4*)(ktb + (size_t)e * 2048 + nb);
#pragma unroll
      for (int q = 0; q < QG; ++q) {
        float qe = qs[q][e];
        d[q][0] = fmaf(qe, kv.x, d[q][0]);
        d[q][1] = fmaf(qe, kv.y, d[q][1]);
        d[q][2] = fmaf(qe, kv.z, d[q][2]);
        d[q][3] = fmaf(qe, kv.w, d[q][3]);
      }
    }
#pragma unroll
    for (int q = 0; q < QG; ++q)
#pragma unroll
      for (int i = 0; i < 4; ++i) sc[q][j * 4 + i] = d[q][i];
  }

#pragma unroll
  for (int q = 0; q < QG; ++q) {
    float m_ = sc[q][0];
#pragma unroll
    for (int j = 1; j < 8; ++j) m_ = fmaxf(m_, sc[q][j]);
#pragma unroll
    for (int off = 1; off < 64; off <<= 1)
      m_ = fmaxf(m_, __shfl_xor(m_, off));
    if (lane == 0) redm[q][wv] = m_;
  }
  __syncthreads();
  float gmax[QG];
#pragma unroll
  for (int q = 0; q < QG; ++q)
    gmax[q] = fmaxf(fmaxf(redm[q][0], redm[q][1]),
                    fmaxf(redm[q][2], redm[q][3]));

  float lsum[QG] = {};
#pragma unroll
  for (int j = 0; j < 2; ++j) {
#pragma unroll
    for (int q = 0; q < QG; ++q) {
      float4 pe;
      pe.x = __expf(sc[q][j * 4 + 0] - gmax[q]);
      pe.y = __expf(sc[q][j * 4 + 1] - gmax[q]);
      pe.z = __expf(sc[q][j * 4 + 2] - gmax[q]);
      pe.w = __expf(sc[q][j * 4 + 3] - gmax[q]);
      *(float4*)(&p[q][j * 1024 + tid * 4]) = pe;
      lsum[q] += pe.x + pe.y + pe.z + pe.w;
    }
  }
#pragma unroll
  for (int q = 0; q < QG; ++q) {
    float s_ = lsum[q];
#pragma unroll
    for (int off = 1; off < 64; off <<= 1)
      s_ += __shfl_xor(s_, off);
    if (lane == 0) reds[q][wv] = s_;
  }
  __syncthreads();
  float denom[QG];
#pragma unroll
  for (int q = 0; q < QG; ++q)
    denom[q] = reds[q][0] + reds[q][1] + reds[q][2] + reds[q][3];

  float acc[QG] = {};
  for (int n = wv * 512; n < wv * 512 + 512; ++n) {
    float v = V[(((size_t)n * 4 + b) * 8 + h) * 64 + lane];
#pragma unroll
    for (int q = 0; q < QG; ++q) acc[q] = fmaf(p[q][n], v, acc[q]);
  }
#pragma unroll
  for (int q = 0; q < QG; ++q) pvp[wv][q][lane] = acc[q];
  __syncthreads();

  for (int i = tid; i < QG * 64; i += 256) {
    int q = i >> 6, e = i & 63;
    float r = (pvp[0][q][e] + pvp[1][q][e] + pvp[2][q][e] + pvp[3][q][e]) /
              denom[q];
    upd[(size_t)(bh * UP + g * QG + q) * 64 + e] = r;
  }
}

// ---------------------------------------------------------------------------
// ctx fill + scatter
// ---------------------------------------------------------------------------
__global__ void fillctx_kernel(const float* __restrict__ meanV,
                               float* __restrict__ ctx) {
  size_t i = ((size_t)blockIdx.x * 256 + threadIdx.x) * 4;
  int d = (int)(i & 511);
  int b = (int)(i >> 20);
  float4 v = *(const float4*)(meanV + (b << 9) + d);
  *(float4*)(ctx + i) = v;
}

__global__ void scatter_kernel(const float* __restrict__ upd,
                               const int* __restrict__ Mtop,
                               float* __restrict__ ctx) {
  const int blk = blockIdx.x;   // bh*40 + s
  const int bh = blk / UP;
  const int b = bh >> 3, h = bh & 7;
  const int n = Mtop[blk];
  ctx[((size_t)(b * 2048 + n)) * 512 + h * 64 + threadIdx.x] =
      upd[(size_t)blk * 64 + threadIdx.x];
}

// ---------------------------------------------------------------------------
// Workspace layout (~68.5 MiB used; ws >= 113 MiB proven in R4):
//   [0,       256K)    Mbuf   32*2048 f32
//   [256K,    576K)    upd    1280*64 f32
//   [589824,  598016)  mnV    32*64 f32
//   [598016,  603136)  Mtop   1280 i32
//   [634880,  897024)  vpart  32*2048 f32
//   [903168,  935936)  flags  8192 i32
//   [935936,  935940)  cnt    1 i32
//   [936192,  941312)  rows   1280 i32
//   [941312,  949504)  mo     4*512 f32
//   [1M, 17M) Q (ctx alias)   [17M, 33M) K   [33M, 49M) V   [49M, 65M) Kt
//   [65M..68M) Wh/Wl planes: 6 x 512 KiB (q,k,v)
// ---------------------------------------------------------------------------
extern "C" void kernel_launch(void* const* d_in, const int* in_sizes, int n_in,
                              void* d_out, int out_size, void* d_ws,
                              size_t ws_size, hipStream_t stream) {
  const float* query = (const float*)d_in[0];
  const float* key   = (const float*)d_in[1];
  const float* value = (const float*)d_in[2];
  const int*   idxs  = (const int*)d_in[3];
  const float* Wq = (const float*)d_in[4];
  const float* bq = (const float*)d_in[5];
  const float* Wk = (const float*)d_in[6];
  const float* bk = (const float*)d_in[7];
  const float* Wv = (const float*)d_in[8];
  const float* bv = (const float*)d_in[9];
  const float* Wo = (const float*)d_in[10];
  const float* bo = (const float*)d_in[11];
  float* out = (float*)d_out;    // reference output dtype is float32

  char* ws = (char*)d_ws;
  float*  Mbuf  = (float*)(ws + 0);
  float*  upd   = (float*)(ws + 262144);
  float*  mnV   = (float*)(ws + 589824);
  int*    Mtop  = (int*)  (ws + 598016);
  float*  vpart = (float*)(ws + 634880);
  int*    flags = (int*)  (ws + 903168);
  int*    cnt   = (int*)  (ws + 935936);
  int*    rows  = (int*)  (ws + 936192);
  float*  mo    = (float*)(ws + 941312);
  float*  Q     = (float*)(ws + MiB(1));
  float*  K     = (float*)(ws + MiB(17));
  float*  V     = (float*)(ws + MiB(33));
  float*  Kt    = (float*)(ws + MiB(49));
  ushort* Whq   = (ushort*)(ws + MiB(65));
  ushort* Wlq   = (ushort*)(ws + MiB(65) + 524288);
  ushort* Whk   = (ushort*)(ws + MiB(66));
  ushort* Wlk   = (ushort*)(ws + MiB(66) + 524288);
  ushort* Whv   = (ushort*)(ws + MiB(67));
  ushort* Wlv   = (ushort*)(ws + MiB(67) + 524288);
  float*  ctx   = Q;   // Q dead after attn_kernel; ctx written afterwards

  // zero flags + cnt (contiguous region)
  hipMemsetAsync(flags, 0, 32768 + 4, stream);

  wsplit_kernel<<<512, 256, 0, stream>>>(Wq, Whq, Wlq);
  wsplit_kernel<<<512, 256, 0, stream>>>(Wk, Whk, Wlk);
  wsplit_kernel<<<512, 256, 0, stream>>>(Wv, Whv, Wlv);

  gemm_mfma<<<512, 256, 0, stream>>>(query, Whq, Wlq, bq, 0.125f, Q);
  gemm_mfma<<<512, 256, 0, stream>>>(key,   Whk, Wlk, bk, 1.0f,   K);
  gemm_mfma<<<512, 256, 0, stream>>>(value, Whv, Wlv, bv, 1.0f,   V);

  transposeK_kernel<<<512, 256, 0, stream>>>(K, Kt);

  mscore_kernel<<<16384, 256, 0, stream>>>(Q, K, idxs, Mbuf);
  topk_kernel<<<NBH, 256, 0, stream>>>(Mbuf, Mtop);
  selbuild_kernel<<<20, 64, 0, stream>>>(Mtop, flags);
  selcompact_kernel<<<32, 256, 0, stream>>>(flags, rows, cnt);

  meanv_part<<<256, 256, 0, stream>>>(V, vpart);
  meanv_final<<<8, 256, 0, stream>>>(vpart, mnV);
  attn_kernel<<<NBH * 8, 256, 0, stream>>>(Q, Kt, V, Mtop, upd);

  fillctx_kernel<<<4096, 256, 0, stream>>>(mnV, ctx);
  scatter_kernel<<<NBH * UP, 64, 0, stream>>>(upd, Mtop, ctx);

  meanout_kernel<<<4, 256, 0, stream>>>(mnV, Wo, bo, mo);
  fillout_kernel<<<4096, 256, 0, stream>>>(mo, out);
  gemm_rows<<<160, 256, 0, stream>>>(ctx, Wo, bo, rows, cnt, out);
}

// Round 13
// 376.965 us; speedup vs baseline: 1.1172x; 1.0021x over previous
//
#include <hip/hip_runtime.h>
#include <hip/hip_bf16.h>

// Problem constants
#define KN 2048
#define BB 4
#define DM 512
#define NH 8
#define HE 64
#define UP 40
#define NBH 32          // B*H
#define NROWS 8192      // KN*B
#define MiB(x) ((size_t)(x) << 20)

typedef __attribute__((ext_vector_type(8))) short short8;
typedef __attribute__((ext_vector_type(4))) float f32x4;

// bf16 split helpers (RNE)
__device__ __forceinline__ ushort f2bf(float x) {
  unsigned u = __float_as_uint(x);
  unsigned r = (u + 0x7FFFu + ((u >> 16) & 1u)) >> 16;
  return (ushort)r;
}
__device__ __forceinline__ float bf2f(ushort h) {
  return __uint_as_float((unsigned)h << 16);
}

// ---------------------------------------------------------------------------
// Split W (512x512 f32, row-major) into hi/lo bf16 planes (row-major ushort).
// ---------------------------------------------------------------------------
__global__ __launch_bounds__(256) void wsplit_kernel(
    const float* __restrict__ W, ushort* __restrict__ Wh,
    ushort* __restrict__ Wl) {
  int i = (blockIdx.x * 256 + threadIdx.x) * 2;   // 512 blocks -> 262144 elems
  float2 v = *(const float2*)(W + i);
  ushort h0 = f2bf(v.x), h1 = f2bf(v.y);
  ushort l0 = f2bf(v.x - bf2f(h0)), l1 = f2bf(v.y - bf2f(h1));
  *(ushort2*)(Wh + i) = make_ushort2(h0, h1);
  *(ushort2*)(Wl + i) = make_ushort2(l0, l1);
}

// ---------------------------------------------------------------------------
// Split-bf16 MFMA GEMM: C[m,o] = (sum_k A[m,k]*W[o,k] + bias[o]) * scale
// 4-term split (AhWh+AhWl+AlWh+AlWl) -> f32-class accuracy (selection-safe).
// Tile 128x64, 512 blocks (XCD-aware decode, FETCH proven 12MB in R11),
// 256 thr = 4 waves; wave w owns rows [w*32,w*32+32) x all 64 cols.
// A staged in LDS as bf16 h/l [128][32]; W fragments read from global bf16
// (L2-resident) -> no B-side LDS traffic. MFMA 16x16x32_bf16:
//   A-frag: lane holds A[lane%16][ (lane/16)*8 + i ]  (bf16x8 contiguous in K)
//   C/D   : col = lane&15, row = (lane>>4)*4 + reg    (m89-verified)
// ---------------------------------------------------------------------------
__global__ __launch_bounds__(256) void gemm_mfma(
    const float* __restrict__ A, const ushort* __restrict__ Wh,
    const ushort* __restrict__ Wl, const float* __restrict__ bias,
    float scale, float* __restrict__ C) {
  __shared__ ushort AsH[128][32];
  __shared__ ushort AsL[128][32];
  const int bid = blockIdx.x;
  const int mt = (bid & 7) * 8 + ((bid >> 3) & 7);  // 0..63
  const int ot = bid >> 6;                          // 0..7
  const int m0 = mt * 128, o0 = ot * 64;
  const int tid = threadIdx.x;
  const int w = tid >> 6, lane = tid & 63;
  const int fr = lane & 15;      // fragment row (A row / W row / C col)
  const int kc = lane >> 4;      // k-chunk (8 bf16)

  f32x4 acc[2][4];
#pragma unroll
  for (int i = 0; i < 2; ++i)
#pragma unroll
    for (int j = 0; j < 4; ++j)
#pragma unroll
      for (int r = 0; r < 4; ++r) acc[i][j][r] = 0.f;

  for (int k0 = 0; k0 < 512; k0 += 32) {
    // stage A tile 128x32 f32 -> bf16 h/l; 1024 float4 / 256 thr = 4 each
#pragma unroll
    for (int i = 0; i < 4; ++i) {
      int flat = tid + i * 256;        // 0..1023
      int r = flat >> 3, c4 = flat & 7;
      float4 av = *(const float4*)(A + (size_t)(m0 + r) * 512 + k0 + c4 * 4);
      ushort h0 = f2bf(av.x), h1 = f2bf(av.y), h2 = f2bf(av.z), h3 = f2bf(av.w);
      ushort l0 = f2bf(av.x - bf2f(h0)), l1 = f2bf(av.y - bf2f(h1));
      ushort l2 = f2bf(av.z - bf2f(h2)), l3 = f2bf(av.w - bf2f(h3));
      *(ushort4*)(&AsH[r][c4 * 4]) = make_ushort4(h0, h1, h2, h3);
      *(ushort4*)(&AsL[r][c4 * 4]) = make_ushort4(l0, l1, l2, l3);
    }
    __syncthreads();

    short8 ah[2], al[2], bh[4], bl[4];
#pragma unroll
    for (int i = 0; i < 2; ++i) {
      ah[i] = *(const short8*)(&AsH[w * 32 + i * 16 + fr][kc * 8]);
      al[i] = *(const short8*)(&AsL[w * 32 + i * 16 + fr][kc * 8]);
    }
#pragma unroll
    for (int j = 0; j < 4; ++j) {
      size_t off = (size_t)(o0 + j * 16 + fr) * 512 + k0 + kc * 8;
      bh[j] = *(const short8*)(Wh + off);
      bl[j] = *(const short8*)(Wl + off);
    }
#pragma unroll
    for (int i = 0; i < 2; ++i)
#pragma unroll
      for (int j = 0; j < 4; ++j) {
        acc[i][j] = __builtin_amdgcn_mfma_f32_16x16x32_bf16(ah[i], bh[j], acc[i][j], 0, 0, 0);
        acc[i][j] = __builtin_amdgcn_mfma_f32_16x16x32_bf16(ah[i], bl[j], acc[i][j], 0, 0, 0);
        acc[i][j] = __builtin_amdgcn_mfma_f32_16x16x32_bf16(al[i], bh[j], acc[i][j], 0, 0, 0);
        acc[i][j] = __builtin_amdgcn_mfma_f32_16x16x32_bf16(al[i], bl[j], acc[i][j], 0, 0, 0);
      }
    __syncthreads();
  }

#pragma unroll
  for (int i = 0; i < 2; ++i)
#pragma unroll
    for (int j = 0; j < 4; ++j)
#pragma unroll
      for (int r = 0; r < 4; ++r) {
        int m = m0 + w * 32 + i * 16 + (lane >> 4) * 4 + r;
        int o = o0 + j * 16 + fr;
        C[(size_t)m * 512 + o] = (acc[i][j][r] + bias[o]) * scale;
      }
}

// ---------------------------------------------------------------------------
// Transpose K into Kt[bh][e][n] for coalesced attention score reads.
// ---------------------------------------------------------------------------
__global__ __launch_bounds__(256) void transposeK_kernel(
    const float* __restrict__ K, float* __restrict__ Kt) {
  const int bh = blockIdx.x & 31;
  const int nt = blockIdx.x >> 5;       // 0..15
  const int b = bh >> 3, h = bh & 7;
  const int n0 = nt * 128;
  const int tid = threadIdx.x;
  __shared__ float T[128][65];

#pragma unroll
  for (int i = 0; i < 8; ++i) {
    int flat = tid + i * 256;           // 0..2047
    int r = flat >> 4;                  // 0..127
    int c4 = flat & 15;                 // 0..15
    float4 v = *(const float4*)(K + (((size_t)(n0 + r) * 4 + b) * 8 + h) * 64 + c4 * 4);
    T[r][c4 * 4 + 0] = v.x; T[r][c4 * 4 + 1] = v.y;
    T[r][c4 * 4 + 2] = v.z; T[r][c4 * 4 + 3] = v.w;
  }
  __syncthreads();

  const int nl = tid & 127;             // 0..127
  const int eg = tid >> 7;              // 0..1
#pragma unroll
  for (int e = eg * 32; e < eg * 32 + 32; ++e)
    Kt[((size_t)bh * 64 + e) * 2048 + n0 + nl] = T[nl][e];
}

// ---------------------------------------------------------------------------
// M scores, wave-cooperative gather. One wave per (bh, n).
// ---------------------------------------------------------------------------
__global__ __launch_bounds__(256) void mscore_kernel(
    const float* __restrict__ Q, const float* __restrict__ K,
    const int* __restrict__ idx, float* __restrict__ Mout) {
  const int bh = blockIdx.x & 31;
  const int c  = blockIdx.x >> 5;        // 0..511
  const int wv = threadIdx.x >> 6;       // 0..3
  const int lane = threadIdx.x & 63;
  const int n = c * 4 + wv;
  const int b = bh >> 3, h = bh & 7;
  const int g = lane >> 4;               // sample group 0..3
  const int e16 = lane & 15;             // element chunk within row

  const float4 qv = *(const float4*)(Q + (((size_t)n * 4 + b) * 8 + h) * 64 + e16 * 4);

  float mx = -INFINITY, sm = 0.f;
#pragma unroll
  for (int it = 0; it < 10; ++it) {
    const int s = it * 4 + g;
    const int kn = idx[n * UP + s];
    const float4 kv = *(const float4*)(K + (((size_t)kn * 4 + b) * 8 + h) * 64 + e16 * 4);
    float d = qv.x * kv.x + qv.y * kv.y + qv.z * kv.z + qv.w * kv.w;
    d += __shfl_xor(d, 1);
    d += __shfl_xor(d, 2);
    d += __shfl_xor(d, 4);
    d += __shfl_xor(d, 8);
    mx = fmaxf(mx, d);
    sm += d;
  }
  mx = fmaxf(mx, __shfl_xor(mx, 16));
  mx = fmaxf(mx, __shfl_xor(mx, 32));
  sm += __shfl_xor(sm, 16);
  sm += __shfl_xor(sm, 32);
  if (lane == 0) Mout[(size_t)bh * 2048 + n] = mx - sm * (1.0f / (float)KN);
}

// ---------------------------------------------------------------------------
// top-40 per (b,h): iterative argmax, lowest-index tiebreak
// ---------------------------------------------------------------------------
__global__ __launch_bounds__(256) void topk_kernel(
    const float* __restrict__ M, int* __restrict__ Mtop) {
  const int bh = blockIdx.x;
  __shared__ float vals[2048];
  __shared__ float rv[256];
  __shared__ int ri[256];
  const float* Mrow = M + (size_t)bh * 2048;
  for (int i = threadIdx.x; i < 2048; i += 256) vals[i] = Mrow[i];
  __syncthreads();
  for (int it = 0; it < UP; ++it) {
    float bv = -INFINITY; int bi = 0x7fffffff;
    for (int i = threadIdx.x; i < 2048; i += 256) {
      float v = vals[i];
      if (v > bv) { bv = v; bi = i; }
    }
    rv[threadIdx.x] = bv; ri[threadIdx.x] = bi;
    __syncthreads();
    for (int st = 128; st; st >>= 1) {
      if (threadIdx.x < st) {
        float ov = rv[threadIdx.x + st]; int oi = ri[threadIdx.x + st];
        float cv = rv[threadIdx.x];      int ci = ri[threadIdx.x];
        if (ov > cv || (ov == cv && oi < ci)) { rv[threadIdx.x] = ov; ri[threadIdx.x] = oi; }
      }
      __syncthreads();
    }
    if (threadIdx.x == 0) { Mtop[bh * UP + it] = ri[0]; vals[ri[0]] = -INFINITY; }
    __syncthreads();
  }
}

// ---------------------------------------------------------------------------
// mean of V: two-phase coalesced column-sum (V is a [2048][2048] matrix).
// ---------------------------------------------------------------------------
__global__ __launch_bounds__(256) void meanv_part(
    const float* __restrict__ V, float* __restrict__ part) {
  const int rc = blockIdx.x >> 3;      // 0..31
  const int cc = blockIdx.x & 7;       // 0..7
  const int c = cc * 256 + threadIdx.x;
  const float* p = V + (size_t)rc * 64 * 2048 + c;
  float acc = 0.f;
#pragma unroll 8
  for (int i = 0; i < 64; ++i) acc += p[(size_t)i * 2048];
  part[(size_t)rc * 2048 + c] = acc;
}

__global__ __launch_bounds__(256) void meanv_final(
    const float* __restrict__ part, float* __restrict__ mnV) {
  const int c = blockIdx.x * 256 + threadIdx.x;   // 8 blocks
  float acc = 0.f;
#pragma unroll
  for (int r = 0; r < 32; ++r) acc += part[(size_t)r * 2048 + c];
  mnV[c] = acc * (1.0f / (float)KN);
}

// ---------------------------------------------------------------------------
// Selected-row machinery for the sparse output GEMM.
// ---------------------------------------------------------------------------
__global__ void selbuild_kernel(const int* __restrict__ Mtop,
                                int* __restrict__ flags) {
  const int i = blockIdx.x * 64 + threadIdx.x;   // 0..1279
  const int bh = i / UP;
  const int b = bh >> 3;
  flags[b * 2048 + Mtop[i]] = 1;
}

__global__ void selcompact_kernel(const int* __restrict__ flags,
                                  int* __restrict__ rows,
                                  int* __restrict__ cnt) {
  const int i = blockIdx.x * 256 + threadIdx.x;  // 0..8191
  if (flags[i]) {
    int p = atomicAdd(cnt, 1);
    rows[p] = i;                                  // flat row index b*2048+n
  }
}

// meanout[b][o] = dot(mnV[b*512..], Wo[o]) + bo[o]
__global__ __launch_bounds__(256) void meanout_kernel(
    const float* __restrict__ mnV, const float* __restrict__ Wo,
    const float* __restrict__ bo, float* __restrict__ mo) {
  const int b = blockIdx.x;           // 4 blocks
  for (int o = threadIdx.x; o < 512; o += 256) {
    const float* m = mnV + b * 512;
    const float* w = Wo + (size_t)o * 512;
    float acc = 0.f;
#pragma unroll 8
    for (int k = 0; k < 512; ++k) acc = fmaf(m[k], w[k], acc);
    mo[b * 512 + o] = acc + bo[o];
  }
}

// out[(b*2048+n)*512 + d] = mo[b*512 + d]  (broadcast fill, float4)
__global__ void fillout_kernel(const float* __restrict__ mo,
                               float* __restrict__ out) {
  size_t i = ((size_t)blockIdx.x * 256 + threadIdx.x) * 4;
  int d = (int)(i & 511);
  int b = (int)(i >> 20);
  float4 v = *(const float4*)(mo + (b << 9) + d);
  *(float4*)(out + i) = v;
}

// ---------------------------------------------------------------------------
// Sparse output GEMM over selected rows only (<=1280 of 8192).
// ---------------------------------------------------------------------------
__global__ __launch_bounds__(256) void gemm_rows(
    const float* __restrict__ ctx, const float* __restrict__ W,
    const float* __restrict__ bias, const int* __restrict__ rows,
    const int* __restrict__ cnt, float* __restrict__ out) {
  __shared__ float As[32][68];
  __shared__ float Ws[32][68];
  __shared__ int rsel[64];
  const int rt = blockIdx.x >> 3;      // 0..19
  const int ot = blockIdx.x & 7;       // 0..7
  const int o0 = ot * 64;
  const int tid = threadIdx.x;
  const int tx = tid & 15;
  const int ty = tid >> 4;
  const int n = *cnt;

  if (rt * 64 >= n) return;            // whole tile out of range

  if (tid < 64) {
    int g = rt * 64 + tid;
    rsel[tid] = (g < n) ? rows[g] : rows[0];
  }
  __syncthreads();

  float acc[4][4] = {};
  for (int k0 = 0; k0 < 512; k0 += 32) {
#pragma unroll
    for (int i = 0; i < 2; ++i) {
      int flat = tid + i * 256;        // 0..511
      int r = flat >> 3;               // 0..63
      int c4 = flat & 7;
      float4 av = *(const float4*)(ctx + (size_t)rsel[r] * 512 + k0 + c4 * 4);
      float4 wv = *(const float4*)(W + (size_t)(o0 + r) * 512 + k0 + c4 * 4);
      As[c4 * 4 + 0][r] = av.x; As[c4 * 4 + 1][r] = av.y;
      As[c4 * 4 + 2][r] = av.z; As[c4 * 4 + 3][r] = av.w;
      Ws[c4 * 4 + 0][r] = wv.x; Ws[c4 * 4 + 1][r] = wv.y;
      Ws[c4 * 4 + 2][r] = wv.z; Ws[c4 * 4 + 3][r] = wv.w;
    }
    __syncthreads();
#pragma unroll
    for (int kk = 0; kk < 32; ++kk) {
      float a_[4], w_[4];
#pragma unroll
      for (int i = 0; i < 4; ++i) a_[i] = As[kk][ty * 4 + i];
#pragma unroll
      for (int j = 0; j < 4; ++j) w_[j] = Ws[kk][tx * 4 + j];
#pragma unroll
      for (int i = 0; i < 4; ++i)
#pragma unroll
        for (int j = 0; j < 4; ++j)
          acc[i][j] = fmaf(a_[i], w_[j], acc[i][j]);
    }
    __syncthreads();
  }

#pragma unroll
  for (int i = 0; i < 4; ++i) {
    int g = rt * 64 + ty * 4 + i;
    if (g < n) {
      int m = rsel[ty * 4 + i];
#pragma unroll
      for (int j = 0; j < 4; ++j) {
        int o = o0 + tx * 4 + j;
        out[(size_t)m * 512 + o] = acc[i][j] + bias[o];
      }
    }
  }
}

// ---------------------------------------------------------------------------
// Batched attention: one block per (bh, group of 5 queries), 256 blocks.
// ---------------------------------------------------------------------------
#define QG 5   // queries per block
__global__ __launch_bounds__(256) void attn_kernel(
    const float* __restrict__ Q, const float* __restrict__ Kt,
    const float* __restrict__ V, const int* __restrict__ Mtop,
    float* __restrict__ upd) {
  const int bh = blockIdx.x >> 3;
  const int g  = blockIdx.x & 7;        // query group
  const int b = bh >> 3, h = bh & 7;
  const int tid = threadIdx.x;
  const int wv = tid >> 6, lane = tid & 63;

  __shared__ float qs[QG][64];
  __shared__ float p[QG][2048];
  __shared__ float redm[QG][4];
  __shared__ float reds[QG][4];
  __shared__ float pvp[4][QG][64];

  for (int i = tid; i < QG * 64; i += 256) {
    int q = i >> 6, e = i & 63;
    int nq = Mtop[bh * UP + g * QG + q];
    qs[q][e] = Q[(((size_t)nq * 4 + b) * 8 + h) * 64 + e];
  }
  __syncthreads();

  const float* ktb = Kt + (size_t)bh * 64 * 2048;
  float sc[QG][8];
#pragma unroll
  for (int j = 0; j < 2; ++j) {
    const int nb = j * 1024 + tid * 4;
    float d[QG][4] = {};
    for (int e = 0; e < 64; ++e) {
      float4 kv = *(const float4*)(ktb + (size_t)e * 2048 + nb);
#pragma unroll
      for (int q = 0; q < QG; ++q) {
        float qe = qs[q][e];
        d[q][0] = fmaf(qe, kv.x, d[q][0]);
        d[q][1] = fmaf(qe, kv.y, d[q][1]);
        d[q][2] = fmaf(qe, kv.z, d[q][2]);
        d[q][3] = fmaf(qe, kv.w, d[q][3]);
      }
    }
#pragma unroll
    for (int q = 0; q < QG; ++q)
#pragma unroll
      for (int i = 0; i < 4; ++i) sc[q][j * 4 + i] = d[q][i];
  }

#pragma unroll
  for (int q = 0; q < QG; ++q) {
    float m_ = sc[q][0];
#pragma unroll
    for (int j = 1; j < 8; ++j) m_ = fmaxf(m_, sc[q][j]);
#pragma unroll
    for (int off = 1; off < 64; off <<= 1)
      m_ = fmaxf(m_, __shfl_xor(m_, off));
    if (lane == 0) redm[q][wv] = m_;
  }
  __syncthreads();
  float gmax[QG];
#pragma unroll
  for (int q = 0; q < QG; ++q)
    gmax[q] = fmaxf(fmaxf(redm[q][0], redm[q][1]),
                    fmaxf(redm[q][2], redm[q][3]));

  float lsum[QG] = {};
#pragma unroll
  for (int j = 0; j < 2; ++j) {
#pragma unroll
    for (int q = 0; q < QG; ++q) {
      float4 pe;
      pe.x = __expf(sc[q][j * 4 + 0] - gmax[q]);
      pe.y = __expf(sc[q][j * 4 + 1] - gmax[q]);
      pe.z = __expf(sc[q][j * 4 + 2] - gmax[q]);
      pe.w = __expf(sc[q][j * 4 + 3] - gmax[q]);
      *(float4*)(&p[q][j * 1024 + tid * 4]) = pe;
      lsum[q] += pe.x + pe.y + pe.z + pe.w;
    }
  }
#pragma unroll
  for (int q = 0; q < QG; ++q) {
    float s_ = lsum[q];
#pragma unroll
    for (int off = 1; off < 64; off <<= 1)
      s_ += __shfl_xor(s_, off);
    if (lane == 0) reds[q][wv] = s_;
  }
  __syncthreads();
  float denom[QG];
#pragma unroll
  for (int q = 0; q < QG; ++q)
    denom[q] = reds[q][0] + reds[q][1] + reds[q][2] + reds[q][3];

  float acc[QG] = {};
  for (int n = wv * 512; n < wv * 512 + 512; ++n) {
    float v = V[(((size_t)n * 4 + b) * 8 + h) * 64 + lane];
#pragma unroll
    for (int q = 0; q < QG; ++q) acc[q] = fmaf(p[q][n], v, acc[q]);
  }
#pragma unroll
  for (int q = 0; q < QG; ++q) pvp[wv][q][lane] = acc[q];
  __syncthreads();

  for (int i = tid; i < QG * 64; i += 256) {
    int q = i >> 6, e = i & 63;
    float r = (pvp[0][q][e] + pvp[1][q][e] + pvp[2][q][e] + pvp[3][q][e]) /
              denom[q];
    upd[(size_t)(bh * UP + g * QG + q) * 64 + e] = r;
  }
}

// ---------------------------------------------------------------------------
// ctx fill + scatter
// ---------------------------------------------------------------------------
__global__ void fillctx_kernel(const float* __restrict__ meanV,
                               float* __restrict__ ctx) {
  size_t i = ((size_t)blockIdx.x * 256 + threadIdx.x) * 4;
  int d = (int)(i & 511);
  int b = (int)(i >> 20);
  float4 v = *(const float4*)(meanV + (b << 9) + d);
  *(float4*)(ctx + i) = v;
}

__global__ void scatter_kernel(const float* __restrict__ upd,
                               const int* __restrict__ Mtop,
                               float* __restrict__ ctx) {
  const int blk = blockIdx.x;   // bh*40 + s
  const int bh = blk / UP;
  const int b = bh >> 3, h = bh & 7;
  const int n = Mtop[blk];
  ctx[((size_t)(b * 2048 + n)) * 512 + h * 64 + threadIdx.x] =
      upd[(size_t)blk * 64 + threadIdx.x];
}

// ---------------------------------------------------------------------------
// Workspace layout (~68.5 MiB used; ws >= 113 MiB proven in R4):
//   [0,       256K)    Mbuf   32*2048 f32
//   [256K,    576K)    upd    1280*64 f32
//   [589824,  598016)  mnV    32*64 f32
//   [598016,  603136)  Mtop   1280 i32
//   [634880,  897024)  vpart  32*2048 f32
//   [903168,  935936)  flags  8192 i32
//   [935936,  935940)  cnt    1 i32
//   [936192,  941312)  rows   1280 i32
//   [941312,  949504)  mo     4*512 f32
//   [1M, 17M) Q (ctx alias)   [17M, 33M) K   [33M, 49M) V   [49M, 65M) Kt
//   [65M..68M) Wh/Wl planes: 6 x 512 KiB (q,k,v)
// ---------------------------------------------------------------------------
extern "C" void kernel_launch(void* const* d_in, const int* in_sizes, int n_in,
                              void* d_out, int out_size, void* d_ws,
                              size_t ws_size, hipStream_t stream) {
  const float* query = (const float*)d_in[0];
  const float* key   = (const float*)d_in[1];
  const float* value = (const float*)d_in[2];
  const int*   idxs  = (const int*)d_in[3];
  const float* Wq = (const float*)d_in[4];
  const float* bq = (const float*)d_in[5];
  const float* Wk = (const float*)d_in[6];
  const float* bk = (const float*)d_in[7];
  const float* Wv = (const float*)d_in[8];
  const float* bv = (const float*)d_in[9];
  const float* Wo = (const float*)d_in[10];
  const float* bo = (const float*)d_in[11];
  float* out = (float*)d_out;    // reference output dtype is float32

  char* ws = (char*)d_ws;
  float*  Mbuf  = (float*)(ws + 0);
  float*  upd   = (float*)(ws + 262144);
  float*  mnV   = (float*)(ws + 589824);
  int*    Mtop  = (int*)  (ws + 598016);
  float*  vpart = (float*)(ws + 634880);
  int*    flags = (int*)  (ws + 903168);
  int*    cnt   = (int*)  (ws + 935936);
  int*    rows  = (int*)  (ws + 936192);
  float*  mo    = (float*)(ws + 941312);
  float*  Q     = (float*)(ws + MiB(1));
  float*  K     = (float*)(ws + MiB(17));
  float*  V     = (float*)(ws + MiB(33));
  float*  Kt    = (float*)(ws + MiB(49));
  ushort* Whq   = (ushort*)(ws + MiB(65));
  ushort* Wlq   = (ushort*)(ws + MiB(65) + 524288);
  ushort* Whk   = (ushort*)(ws + MiB(66));
  ushort* Wlk   = (ushort*)(ws + MiB(66) + 524288);
  ushort* Whv   = (ushort*)(ws + MiB(67));
  ushort* Wlv   = (ushort*)(ws + MiB(67) + 524288);
  float*  ctx   = Q;   // Q dead after attn_kernel; ctx written afterwards

  // zero flags + cnt (contiguous region)
  hipMemsetAsync(flags, 0, 32768 + 4, stream);

  wsplit_kernel<<<512, 256, 0, stream>>>(Wq, Whq, Wlq);
  wsplit_kernel<<<512, 256, 0, stream>>>(Wk, Whk, Wlk);
  wsplit_kernel<<<512, 256, 0, stream>>>(Wv, Whv, Wlv);

  gemm_mfma<<<512, 256, 0, stream>>>(query, Whq, Wlq, bq, 0.125f, Q);
  gemm_mfma<<<512, 256, 0, stream>>>(key,   Whk, Wlk, bk, 1.0f,   K);
  gemm_mfma<<<512, 256, 0, stream>>>(value, Whv, Wlv, bv, 1.0f,   V);

  transposeK_kernel<<<512, 256, 0, stream>>>(K, Kt);

  mscore_kernel<<<16384, 256, 0, stream>>>(Q, K, idxs, Mbuf);
  topk_kernel<<<NBH, 256, 0, stream>>>(Mbuf, Mtop);
  selbuild_kernel<<<20, 64, 0, stream>>>(Mtop, flags);
  selcompact_kernel<<<32, 256, 0, stream>>>(flags, rows, cnt);

  meanv_part<<<256, 256, 0, stream>>>(V, vpart);
  meanv_final<<<8, 256, 0, stream>>>(vpart, mnV);
  attn_kernel<<<NBH * 8, 256, 0, stream>>>(Q, Kt, V, Mtop, upd);

  fillctx_kernel<<<4096, 256, 0, stream>>>(mnV, ctx);
  scatter_kernel<<<NBH * UP, 64, 0, stream>>>(upd, Mtop, ctx);

  meanout_kernel<<<4, 256, 0, stream>>>(mnV, Wo, bo, mo);
  fillout_kernel<<<4096, 256, 0, stream>>>(mo, out);
  gemm_rows<<<160, 256, 0, stream>>>(ctx, Wo, bo, rows, cnt, out);
}

// Round 14
// 332.087 us; speedup vs baseline: 1.2682x; 1.1351x over previous
//
#include <hip/hip_runtime.h>
#include <hip/hip_bf16.h>

// Problem constants
#define KN 2048
#define BB 4
#define DM 512
#define NH 8
#define HE 64
#define UP 40
#define NBH 32          // B*H
#define NROWS 8192      // KN*B
#define MiB(x) ((size_t)(x) << 20)

typedef __attribute__((ext_vector_type(8))) short short8;
typedef __attribute__((ext_vector_type(4))) float f32x4;

// bf16 split helpers (RNE)
__device__ __forceinline__ ushort f2bf(float x) {
  unsigned u = __float_as_uint(x);
  unsigned r = (u + 0x7FFFu + ((u >> 16) & 1u)) >> 16;
  return (ushort)r;
}
__device__ __forceinline__ float bf2f(ushort h) {
  return __uint_as_float((unsigned)h << 16);
}

// ---------------------------------------------------------------------------
// Split W (512x512 f32, row-major) into hi/lo bf16 planes (row-major ushort).
// ---------------------------------------------------------------------------
__global__ __launch_bounds__(256) void wsplit_kernel(
    const float* __restrict__ W, ushort* __restrict__ Wh,
    ushort* __restrict__ Wl) {
  int i = (blockIdx.x * 256 + threadIdx.x) * 2;   // 512 blocks -> 262144 elems
  float2 v = *(const float2*)(W + i);
  ushort h0 = f2bf(v.x), h1 = f2bf(v.y);
  ushort l0 = f2bf(v.x - bf2f(h0)), l1 = f2bf(v.y - bf2f(h1));
  *(ushort2*)(Wh + i) = make_ushort2(h0, h1);
  *(ushort2*)(Wl + i) = make_ushort2(l0, l1);
}

// ---------------------------------------------------------------------------
// Split-bf16 MFMA GEMM: C[m,o] = (sum_k A[m,k]*W[o,k] + bias[o]) * scale
// (unchanged from R13 — verified 4-term split, selection-safe)
// ---------------------------------------------------------------------------
__global__ __launch_bounds__(256) void gemm_mfma(
    const float* __restrict__ A, const ushort* __restrict__ Wh,
    const ushort* __restrict__ Wl, const float* __restrict__ bias,
    float scale, float* __restrict__ C) {
  __shared__ ushort AsH[128][32];
  __shared__ ushort AsL[128][32];
  const int bid = blockIdx.x;
  const int mt = (bid & 7) * 8 + ((bid >> 3) & 7);  // 0..63
  const int ot = bid >> 6;                          // 0..7
  const int m0 = mt * 128, o0 = ot * 64;
  const int tid = threadIdx.x;
  const int w = tid >> 6, lane = tid & 63;
  const int fr = lane & 15;      // fragment row (A row / W row / C col)
  const int kc = lane >> 4;      // k-chunk (8 bf16)

  f32x4 acc[2][4];
#pragma unroll
  for (int i = 0; i < 2; ++i)
#pragma unroll
    for (int j = 0; j < 4; ++j)
#pragma unroll
      for (int r = 0; r < 4; ++r) acc[i][j][r] = 0.f;

  for (int k0 = 0; k0 < 512; k0 += 32) {
#pragma unroll
    for (int i = 0; i < 4; ++i) {
      int flat = tid + i * 256;        // 0..1023
      int r = flat >> 3, c4 = flat & 7;
      float4 av = *(const float4*)(A + (size_t)(m0 + r) * 512 + k0 + c4 * 4);
      ushort h0 = f2bf(av.x), h1 = f2bf(av.y), h2 = f2bf(av.z), h3 = f2bf(av.w);
      ushort l0 = f2bf(av.x - bf2f(h0)), l1 = f2bf(av.y - bf2f(h1));
      ushort l2 = f2bf(av.z - bf2f(h2)), l3 = f2bf(av.w - bf2f(h3));
      *(ushort4*)(&AsH[r][c4 * 4]) = make_ushort4(h0, h1, h2, h3);
      *(ushort4*)(&AsL[r][c4 * 4]) = make_ushort4(l0, l1, l2, l3);
    }
    __syncthreads();

    short8 ah[2], al[2], bh[4], bl[4];
#pragma unroll
    for (int i = 0; i < 2; ++i) {
      ah[i] = *(const short8*)(&AsH[w * 32 + i * 16 + fr][kc * 8]);
      al[i] = *(const short8*)(&AsL[w * 32 + i * 16 + fr][kc * 8]);
    }
#pragma unroll
    for (int j = 0; j < 4; ++j) {
      size_t off = (size_t)(o0 + j * 16 + fr) * 512 + k0 + kc * 8;
      bh[j] = *(const short8*)(Wh + off);
      bl[j] = *(const short8*)(Wl + off);
    }
#pragma unroll
    for (int i = 0; i < 2; ++i)
#pragma unroll
      for (int j = 0; j < 4; ++j) {
        acc[i][j] = __builtin_amdgcn_mfma_f32_16x16x32_bf16(ah[i], bh[j], acc[i][j], 0, 0, 0);
        acc[i][j] = __builtin_amdgcn_mfma_f32_16x16x32_bf16(ah[i], bl[j], acc[i][j], 0, 0, 0);
        acc[i][j] = __builtin_amdgcn_mfma_f32_16x16x32_bf16(al[i], bh[j], acc[i][j], 0, 0, 0);
        acc[i][j] = __builtin_amdgcn_mfma_f32_16x16x32_bf16(al[i], bl[j], acc[i][j], 0, 0, 0);
      }
    __syncthreads();
  }

#pragma unroll
  for (int i = 0; i < 2; ++i)
#pragma unroll
    for (int j = 0; j < 4; ++j)
#pragma unroll
      for (int r = 0; r < 4; ++r) {
        int m = m0 + w * 32 + i * 16 + (lane >> 4) * 4 + r;
        int o = o0 + j * 16 + fr;
        C[(size_t)m * 512 + o] = (acc[i][j][r] + bias[o]) * scale;
      }
}

// ---------------------------------------------------------------------------
// Transpose K into Kt[bh][e][n] for coalesced attention score reads.
// ---------------------------------------------------------------------------
__global__ __launch_bounds__(256) void transposeK_kernel(
    const float* __restrict__ K, float* __restrict__ Kt) {
  const int bh = blockIdx.x & 31;
  const int nt = blockIdx.x >> 5;       // 0..15
  const int b = bh >> 3, h = bh & 7;
  const int n0 = nt * 128;
  const int tid = threadIdx.x;
  __shared__ float T[128][65];

#pragma unroll
  for (int i = 0; i < 8; ++i) {
    int flat = tid + i * 256;           // 0..2047
    int r = flat >> 4;                  // 0..127
    int c4 = flat & 15;                 // 0..15
    float4 v = *(const float4*)(K + (((size_t)(n0 + r) * 4 + b) * 8 + h) * 64 + c4 * 4);
    T[r][c4 * 4 + 0] = v.x; T[r][c4 * 4 + 1] = v.y;
    T[r][c4 * 4 + 2] = v.z; T[r][c4 * 4 + 3] = v.w;
  }
  __syncthreads();

  const int nl = tid & 127;             // 0..127
  const int eg = tid >> 7;              // 0..1
#pragma unroll
  for (int e = eg * 32; e < eg * 32 + 32; ++e)
    Kt[((size_t)bh * 64 + e) * 2048 + n0 + nl] = T[nl][e];
}

// ---------------------------------------------------------------------------
// M scores, wave-cooperative gather. One wave per (bh, n).
// ---------------------------------------------------------------------------
__global__ __launch_bounds__(256) void mscore_kernel(
    const float* __restrict__ Q, const float* __restrict__ K,
    const int* __restrict__ idx, float* __restrict__ Mout) {
  const int bh = blockIdx.x & 31;
  const int c  = blockIdx.x >> 5;        // 0..511
  const int wv = threadIdx.x >> 6;       // 0..3
  const int lane = threadIdx.x & 63;
  const int n = c * 4 + wv;
  const int b = bh >> 3, h = bh & 7;
  const int g = lane >> 4;               // sample group 0..3
  const int e16 = lane & 15;             // element chunk within row

  const float4 qv = *(const float4*)(Q + (((size_t)n * 4 + b) * 8 + h) * 64 + e16 * 4);

  float mx = -INFINITY, sm = 0.f;
#pragma unroll
  for (int it = 0; it < 10; ++it) {
    const int s = it * 4 + g;
    const int kn = idx[n * UP + s];
    const float4 kv = *(const float4*)(K + (((size_t)kn * 4 + b) * 8 + h) * 64 + e16 * 4);
    float d = qv.x * kv.x + qv.y * kv.y + qv.z * kv.z + qv.w * kv.w;
    d += __shfl_xor(d, 1);
    d += __shfl_xor(d, 2);
    d += __shfl_xor(d, 4);
    d += __shfl_xor(d, 8);
    mx = fmaxf(mx, d);
    sm += d;
  }
  mx = fmaxf(mx, __shfl_xor(mx, 16));
  mx = fmaxf(mx, __shfl_xor(mx, 32));
  sm += __shfl_xor(sm, 16);
  sm += __shfl_xor(sm, 32);
  if (lane == 0) Mout[(size_t)bh * 2048 + n] = mx - sm * (1.0f / (float)KN);
}

// ---------------------------------------------------------------------------
// top-40 per (b,h) via 4-pass byte radix-select on monotone u32 keys.
// Emits the top-40 SET (order-arbitrary; final output is order-invariant
// since each selected n gets its own attention + scatter slot).
// Ties (key == T) resolved by lowest index (jax semantics).
// ---------------------------------------------------------------------------
__global__ __launch_bounds__(256) void topk_kernel(
    const float* __restrict__ M, int* __restrict__ Mtop) {
  const int bh = blockIdx.x;
  __shared__ unsigned keys[2048];
  __shared__ int hist[256];
  __shared__ int suf[256];
  __shared__ int scal[2];
  __shared__ int ties[128];
  __shared__ int cnts[2];

  const int tid = threadIdx.x;
  const float* Mrow = M + (size_t)bh * 2048;
#pragma unroll
  for (int i = 0; i < 8; ++i) {
    int j = tid + i * 256;
    unsigned u = __float_as_uint(Mrow[j]);
    keys[j] = (u & 0x80000000u) ? ~u : (u | 0x80000000u);  // monotone map
  }
  if (tid < 2) cnts[tid] = 0;

  unsigned prefix = 0, prefmask = 0;
  int rank = UP;
#pragma unroll
  for (int shift = 24; shift >= 0; shift -= 8) {
    hist[tid] = 0;
    __syncthreads();
#pragma unroll
    for (int i = 0; i < 8; ++i) {
      unsigned k = keys[tid + i * 256];
      if ((k & prefmask) == prefix)
        atomicAdd(&hist[(k >> shift) & 0xFFu], 1);
    }
    __syncthreads();
    // parallel inclusive suffix-sum of hist into suf
    suf[tid] = hist[tid];
    __syncthreads();
#pragma unroll
    for (int off = 1; off < 256; off <<= 1) {
      int add = (tid + off < 256) ? suf[tid + off] : 0;
      __syncthreads();
      suf[tid] += add;
      __syncthreads();
    }
    // unique bin B: above(B) < rank <= suf[B], above = suf - hist
    {
      int above = suf[tid] - hist[tid];
      if (above < rank && rank <= suf[tid]) {
        scal[0] = tid;
        scal[1] = rank - above;
      }
    }
    __syncthreads();
    prefix |= ((unsigned)scal[0]) << shift;
    prefmask |= 0xFFu << shift;
    rank = scal[1];
    __syncthreads();
  }
  const unsigned T = prefix;   // exact 40th-largest key; need `rank` of == T

  // emit: keys > T in any order; collect == T candidates
#pragma unroll
  for (int i = 0; i < 8; ++i) {
    int j = tid + i * 256;
    unsigned k = keys[j];
    if (k > T) {
      int p = atomicAdd(&cnts[0], 1);
      Mtop[bh * UP + p] = j;
    } else if (k == T) {
      int p = atomicAdd(&cnts[1], 1);
      if (p < 128) ties[p] = j;
    }
  }
  __syncthreads();
  if (tid == 0) {
    int base = cnts[0];                 // = UP - rank
    int need = UP - base;
    int tc = cnts[1] < 128 ? cnts[1] : 128;
    for (int s = 0; s < need; ++s) {    // pick lowest indices among ties
      int best = 1 << 30, bj = 0;
      for (int j = 0; j < tc; ++j) {
        int v = ties[j];
        if (v < best) { best = v; bj = j; }
      }
      Mtop[bh * UP + base + s] = best;
      ties[bj] = 1 << 30;
    }
  }
}

// ---------------------------------------------------------------------------
// mean of V: two-phase coalesced column-sum (V is a [2048][2048] matrix).
// ---------------------------------------------------------------------------
__global__ __launch_bounds__(256) void meanv_part(
    const float* __restrict__ V, float* __restrict__ part) {
  const int rc = blockIdx.x >> 3;      // 0..31
  const int cc = blockIdx.x & 7;       // 0..7
  const int c = cc * 256 + threadIdx.x;
  const float* p = V + (size_t)rc * 64 * 2048 + c;
  float acc = 0.f;
#pragma unroll 8
  for (int i = 0; i < 64; ++i) acc += p[(size_t)i * 2048];
  part[(size_t)rc * 2048 + c] = acc;
}

__global__ __launch_bounds__(256) void meanv_final(
    const float* __restrict__ part, float* __restrict__ mnV) {
  const int c = blockIdx.x * 256 + threadIdx.x;   // 8 blocks
  float acc = 0.f;
#pragma unroll
  for (int r = 0; r < 32; ++r) acc += part[(size_t)r * 2048 + c];
  mnV[c] = acc * (1.0f / (float)KN);
}

// ---------------------------------------------------------------------------
// Selected-row machinery for the sparse output GEMM.
// ---------------------------------------------------------------------------
__global__ void selbuild_kernel(const int* __restrict__ Mtop,
                                int* __restrict__ flags) {
  const int i = blockIdx.x * 64 + threadIdx.x;   // 0..1279
  const int bh = i / UP;
  const int b = bh >> 3;
  flags[b * 2048 + Mtop[i]] = 1;
}

__global__ void selcompact_kernel(const int* __restrict__ flags,
                                  int* __restrict__ rows,
                                  int* __restrict__ cnt) {
  const int i = blockIdx.x * 256 + threadIdx.x;  // 0..8191
  if (flags[i]) {
    int p = atomicAdd(cnt, 1);
    rows[p] = i;                                  // flat row index b*2048+n
  }
}

// meanout[b][o] = dot(mnV[b*512..], Wo[o]) + bo[o]
__global__ __launch_bounds__(256) void meanout_kernel(
    const float* __restrict__ mnV, const float* __restrict__ Wo,
    const float* __restrict__ bo, float* __restrict__ mo) {
  const int b = blockIdx.x;           // 4 blocks
  for (int o = threadIdx.x; o < 512; o += 256) {
    const float* m = mnV + b * 512;
    const float* w = Wo + (size_t)o * 512;
    float acc = 0.f;
#pragma unroll 8
    for (int k = 0; k < 512; ++k) acc = fmaf(m[k], w[k], acc);
    mo[b * 512 + o] = acc + bo[o];
  }
}

// out[(b*2048+n)*512 + d] = mo[b*512 + d]  (broadcast fill, float4)
__global__ void fillout_kernel(const float* __restrict__ mo,
                               float* __restrict__ out) {
  size_t i = ((size_t)blockIdx.x * 256 + threadIdx.x) * 4;
  int d = (int)(i & 511);
  int b = (int)(i >> 20);
  float4 v = *(const float4*)(mo + (b << 9) + d);
  *(float4*)(out + i) = v;
}

// ---------------------------------------------------------------------------
// Sparse output GEMM over selected rows only (<=1280 of 8192).
// ---------------------------------------------------------------------------
__global__ __launch_bounds__(256) void gemm_rows(
    const float* __restrict__ ctx, const float* __restrict__ W,
    const float* __restrict__ bias, const int* __restrict__ rows,
    const int* __restrict__ cnt, float* __restrict__ out) {
  __shared__ float As[32][68];
  __shared__ float Ws[32][68];
  __shared__ int rsel[64];
  const int rt = blockIdx.x >> 3;      // 0..19
  const int ot = blockIdx.x & 7;       // 0..7
  const int o0 = ot * 64;
  const int tid = threadIdx.x;
  const int tx = tid & 15;
  const int ty = tid >> 4;
  const int n = *cnt;

  if (rt * 64 >= n) return;            // whole tile out of range

  if (tid < 64) {
    int g = rt * 64 + tid;
    rsel[tid] = (g < n) ? rows[g] : rows[0];
  }
  __syncthreads();

  float acc[4][4] = {};
  for (int k0 = 0; k0 < 512; k0 += 32) {
#pragma unroll
    for (int i = 0; i < 2; ++i) {
      int flat = tid + i * 256;        // 0..511
      int r = flat >> 3;               // 0..63
      int c4 = flat & 7;
      float4 av = *(const float4*)(ctx + (size_t)rsel[r] * 512 + k0 + c4 * 4);
      float4 wv = *(const float4*)(W + (size_t)(o0 + r) * 512 + k0 + c4 * 4);
      As[c4 * 4 + 0][r] = av.x; As[c4 * 4 + 1][r] = av.y;
      As[c4 * 4 + 2][r] = av.z; As[c4 * 4 + 3][r] = av.w;
      Ws[c4 * 4 + 0][r] = wv.x; Ws[c4 * 4 + 1][r] = wv.y;
      Ws[c4 * 4 + 2][r] = wv.z; Ws[c4 * 4 + 3][r] = wv.w;
    }
    __syncthreads();
#pragma unroll
    for (int kk = 0; kk < 32; ++kk) {
      float a_[4], w_[4];
#pragma unroll
      for (int i = 0; i < 4; ++i) a_[i] = As[kk][ty * 4 + i];
#pragma unroll
      for (int j = 0; j < 4; ++j) w_[j] = Ws[kk][tx * 4 + j];
#pragma unroll
      for (int i = 0; i < 4; ++i)
#pragma unroll
        for (int j = 0; j < 4; ++j)
          acc[i][j] = fmaf(a_[i], w_[j], acc[i][j]);
    }
    __syncthreads();
  }

#pragma unroll
  for (int i = 0; i < 4; ++i) {
    int g = rt * 64 + ty * 4 + i;
    if (g < n) {
      int m = rsel[ty * 4 + i];
#pragma unroll
      for (int j = 0; j < 4; ++j) {
        int o = o0 + tx * 4 + j;
        out[(size_t)m * 512 + o] = acc[i][j] + bias[o];
      }
    }
  }
}

// ---------------------------------------------------------------------------
// Batched attention: one block per (bh, group of 5 queries), 256 blocks.
// ---------------------------------------------------------------------------
#define QG 5   // queries per block
__global__ __launch_bounds__(256) void attn_kernel(
    const float* __restrict__ Q, const float* __restrict__ Kt,
    const float* __restrict__ V, const int* __restrict__ Mtop,
    float* __restrict__ upd) {
  const int bh = blockIdx.x >> 3;
  const int g  = blockIdx.x & 7;        // query group
  const int b = bh >> 3, h = bh & 7;
  const int tid = threadIdx.x;
  const int wv = tid >> 6, lane = tid & 63;

  __shared__ float qs[QG][64];
  __shared__ float p[QG][2048];
  __shared__ float redm[QG][4];
  __shared__ float reds[QG][4];
  __shared__ float pvp[4][QG][64];

  for (int i = tid; i < QG * 64; i += 256) {
    int q = i >> 6, e = i & 63;
    int nq = Mtop[bh * UP + g * QG + q];
    qs[q][e] = Q[(((size_t)nq * 4 + b) * 8 + h) * 64 + e];
  }
  __syncthreads();

  const float* ktb = Kt + (size_t)bh * 64 * 2048;
  float sc[QG][8];
#pragma unroll
  for (int j = 0; j < 2; ++j) {
    const int nb = j * 1024 + tid * 4;
    float d[QG][4] = {};
    for (int e = 0; e < 64; ++e) {
      float4 kv = *(const float4*)(ktb + (size_t)e * 2048 + nb);
#pragma unroll
      for (int q = 0; q < QG; ++q) {
        float qe = qs[q][e];
        d[q][0] = fmaf(qe, kv.x, d[q][0]);
        d[q][1] = fmaf(qe, kv.y, d[q][1]);
        d[q][2] = fmaf(qe, kv.z, d[q][2]);
        d[q][3] = fmaf(qe, kv.w, d[q][3]);
      }
    }
#pragma unroll
    for (int q = 0; q < QG; ++q)
#pragma unroll
      for (int i = 0; i < 4; ++i) sc[q][j * 4 + i] = d[q][i];
  }

#pragma unroll
  for (int q = 0; q < QG; ++q) {
    float m_ = sc[q][0];
#pragma unroll
    for (int j = 1; j < 8; ++j) m_ = fmaxf(m_, sc[q][j]);
#pragma unroll
    for (int off = 1; off < 64; off <<= 1)
      m_ = fmaxf(m_, __shfl_xor(m_, off));
    if (lane == 0) redm[q][wv] = m_;
  }
  __syncthreads();
  float gmax[QG];
#pragma unroll
  for (int q = 0; q < QG; ++q)
    gmax[q] = fmaxf(fmaxf(redm[q][0], redm[q][1]),
                    fmaxf(redm[q][2], redm[q][3]));

  float lsum[QG] = {};
#pragma unroll
  for (int j = 0; j < 2; ++j) {
#pragma unroll
    for (int q = 0; q < QG; ++q) {
      float4 pe;
      pe.x = __expf(sc[q][j * 4 + 0] - gmax[q]);
      pe.y = __expf(sc[q][j * 4 + 1] - gmax[q]);
      pe.z = __expf(sc[q][j * 4 + 2] - gmax[q]);
      pe.w = __expf(sc[q][j * 4 + 3] - gmax[q]);
      *(float4*)(&p[q][j * 1024 + tid * 4]) = pe;
      lsum[q] += pe.x + pe.y + pe.z + pe.w;
    }
  }
#pragma unroll
  for (int q = 0; q < QG; ++q) {
    float s_ = lsum[q];
#pragma unroll
    for (int off = 1; off < 64; off <<= 1)
      s_ += __shfl_xor(s_, off);
    if (lane == 0) reds[q][wv] = s_;
  }
  __syncthreads();
  float denom[QG];
#pragma unroll
  for (int q = 0; q < QG; ++q)
    denom[q] = reds[q][0] + reds[q][1] + reds[q][2] + reds[q][3];

  float acc[QG] = {};
  for (int n = wv * 512; n < wv * 512 + 512; ++n) {
    float v = V[(((size_t)n * 4 + b) * 8 + h) * 64 + lane];
#pragma unroll
    for (int q = 0; q < QG; ++q) acc[q] = fmaf(p[q][n], v, acc[q]);
  }
#pragma unroll
  for (int q = 0; q < QG; ++q) pvp[wv][q][lane] = acc[q];
  __syncthreads();

  for (int i = tid; i < QG * 64; i += 256) {
    int q = i >> 6, e = i & 63;
    float r = (pvp[0][q][e] + pvp[1][q][e] + pvp[2][q][e] + pvp[3][q][e]) /
              denom[q];
    upd[(size_t)(bh * UP + g * QG + q) * 64 + e] = r;
  }
}

// ---------------------------------------------------------------------------
// ctx fill + scatter
// ---------------------------------------------------------------------------
__global__ void fillctx_kernel(const float* __restrict__ meanV,
                               float* __restrict__ ctx) {
  size_t i = ((size_t)blockIdx.x * 256 + threadIdx.x) * 4;
  int d = (int)(i & 511);
  int b = (int)(i >> 20);
  float4 v = *(const float4*)(meanV + (b << 9) + d);
  *(float4*)(ctx + i) = v;
}

__global__ void scatter_kernel(const float* __restrict__ upd,
                               const int* __restrict__ Mtop,
                               float* __restrict__ ctx) {
  const int blk = blockIdx.x;   // bh*40 + s
  const int bh = blk / UP;
  const int b = bh >> 3, h = bh & 7;
  const int n = Mtop[blk];
  ctx[((size_t)(b * 2048 + n)) * 512 + h * 64 + threadIdx.x] =
      upd[(size_t)blk * 64 + threadIdx.x];
}

// ---------------------------------------------------------------------------
// Workspace layout (~68.5 MiB used; ws >= 113 MiB proven in R4):
//   [0,       256K)    Mbuf   32*2048 f32
//   [256K,    576K)    upd    1280*64 f32
//   [589824,  598016)  mnV    32*64 f32
//   [598016,  603136)  Mtop   1280 i32
//   [634880,  897024)  vpart  32*2048 f32
//   [903168,  935936)  flags  8192 i32
//   [935936,  935940)  cnt    1 i32
//   [936192,  941312)  rows   1280 i32
//   [941312,  949504)  mo     4*512 f32
//   [1M, 17M) Q (ctx alias)   [17M, 33M) K   [33M, 49M) V   [49M, 65M) Kt
//   [65M..68M) Wh/Wl planes: 6 x 512 KiB (q,k,v)
// ---------------------------------------------------------------------------
extern "C" void kernel_launch(void* const* d_in, const int* in_sizes, int n_in,
                              void* d_out, int out_size, void* d_ws,
                              size_t ws_size, hipStream_t stream) {
  const float* query = (const float*)d_in[0];
  const float* key   = (const float*)d_in[1];
  const float* value = (const float*)d_in[2];
  const int*   idxs  = (const int*)d_in[3];
  const float* Wq = (const float*)d_in[4];
  const float* bq = (const float*)d_in[5];
  const float* Wk = (const float*)d_in[6];
  const float* bk = (const float*)d_in[7];
  const float* Wv = (const float*)d_in[8];
  const float* bv = (const float*)d_in[9];
  const float* Wo = (const float*)d_in[10];
  const float* bo = (const float*)d_in[11];
  float* out = (float*)d_out;    // reference output dtype is float32

  char* ws = (char*)d_ws;
  float*  Mbuf  = (float*)(ws + 0);
  float*  upd   = (float*)(ws + 262144);
  float*  mnV   = (float*)(ws + 589824);
  int*    Mtop  = (int*)  (ws + 598016);
  float*  vpart = (float*)(ws + 634880);
  int*    flags = (int*)  (ws + 903168);
  int*    cnt   = (int*)  (ws + 935936);
  int*    rows  = (int*)  (ws + 936192);
  float*  mo    = (float*)(ws + 941312);
  float*  Q     = (float*)(ws + MiB(1));
  float*  K     = (float*)(ws + MiB(17));
  float*  V     = (float*)(ws + MiB(33));
  float*  Kt    = (float*)(ws + MiB(49));
  ushort* Whq   = (ushort*)(ws + MiB(65));
  ushort* Wlq   = (ushort*)(ws + MiB(65) + 524288);
  ushort* Whk   = (ushort*)(ws + MiB(66));
  ushort* Wlk   = (ushort*)(ws + MiB(66) + 524288);
  ushort* Whv   = (ushort*)(ws + MiB(67));
  ushort* Wlv   = (ushort*)(ws + MiB(67) + 524288);
  float*  ctx   = Q;   // Q dead after attn_kernel; ctx written afterwards

  // zero flags + cnt (contiguous region)
  hipMemsetAsync(flags, 0, 32768 + 4, stream);

  wsplit_kernel<<<512, 256, 0, stream>>>(Wq, Whq, Wlq);
  wsplit_kernel<<<512, 256, 0, stream>>>(Wk, Whk, Wlk);
  wsplit_kernel<<<512, 256, 0, stream>>>(Wv, Whv, Wlv);

  gemm_mfma<<<512, 256, 0, stream>>>(query, Whq, Wlq, bq, 0.125f, Q);
  gemm_mfma<<<512, 256, 0, stream>>>(key,   Whk, Wlk, bk, 1.0f,   K);
  gemm_mfma<<<512, 256, 0, stream>>>(value, Whv, Wlv, bv, 1.0f,   V);

  transposeK_kernel<<<512, 256, 0, stream>>>(K, Kt);

  mscore_kernel<<<16384, 256, 0, stream>>>(Q, K, idxs, Mbuf);
  topk_kernel<<<NBH, 256, 0, stream>>>(Mbuf, Mtop);
  selbuild_kernel<<<20, 64, 0, stream>>>(Mtop, flags);
  selcompact_kernel<<<32, 256, 0, stream>>>(flags, rows, cnt);

  meanv_part<<<256, 256, 0, stream>>>(V, vpart);
  meanv_final<<<8, 256, 0, stream>>>(vpart, mnV);
  attn_kernel<<<NBH * 8, 256, 0, stream>>>(Q, Kt, V, Mtop, upd);

  fillctx_kernel<<<4096, 256, 0, stream>>>(mnV, ctx);
  scatter_kernel<<<NBH * UP, 64, 0, stream>>>(upd, Mtop, ctx);

  meanout_kernel<<<4, 256, 0, stream>>>(mnV, Wo, bo, mo);
  fillout_kernel<<<4096, 256, 0, stream>>>(mo, out);
  gemm_rows<<<160, 256, 0, stream>>>(ctx, Wo, bo, rows, cnt, out);
}

// Round 15
// 304.186 us; speedup vs baseline: 1.3845x; 1.0917x over previous
//
#include <hip/hip_runtime.h>
#include <hip/hip_bf16.h>

// Problem constants
#define KN 2048
#define BB 4
#define DM 512
#define NH 8
#define HE 64
#define UP 40
#define NBH 32          // B*H
#define NROWS 8192      // KN*B
#define MiB(x) ((size_t)(x) << 20)

typedef __attribute__((ext_vector_type(8))) short short8;
typedef __attribute__((ext_vector_type(4))) float f32x4;

// bf16 split helpers (RNE)
__device__ __forceinline__ ushort f2bf(float x) {
  unsigned u = __float_as_uint(x);
  unsigned r = (u + 0x7FFFu + ((u >> 16) & 1u)) >> 16;
  return (ushort)r;
}
__device__ __forceinline__ float bf2f(ushort h) {
  return __uint_as_float((unsigned)h << 16);
}

// ---------------------------------------------------------------------------
// Split W (512x512 f32, row-major) into hi/lo bf16 planes (row-major ushort).
// ---------------------------------------------------------------------------
__global__ __launch_bounds__(256) void wsplit_kernel(
    const float* __restrict__ W, ushort* __restrict__ Wh,
    ushort* __restrict__ Wl) {
  int i = (blockIdx.x * 256 + threadIdx.x) * 2;   // 512 blocks -> 262144 elems
  float2 v = *(const float2*)(W + i);
  ushort h0 = f2bf(v.x), h1 = f2bf(v.y);
  ushort l0 = f2bf(v.x - bf2f(h0)), l1 = f2bf(v.y - bf2f(h1));
  *(ushort2*)(Wh + i) = make_ushort2(h0, h1);
  *(ushort2*)(Wl + i) = make_ushort2(l0, l1);
}

// ---------------------------------------------------------------------------
// Split-bf16 MFMA GEMM (R13, verified): C = (A W^T + bias) * scale
// ---------------------------------------------------------------------------
__global__ __launch_bounds__(256) void gemm_mfma(
    const float* __restrict__ A, const ushort* __restrict__ Wh,
    const ushort* __restrict__ Wl, const float* __restrict__ bias,
    float scale, float* __restrict__ C) {
  __shared__ ushort AsH[128][32];
  __shared__ ushort AsL[128][32];
  const int bid = blockIdx.x;
  const int mt = (bid & 7) * 8 + ((bid >> 3) & 7);  // 0..63
  const int ot = bid >> 6;                          // 0..7
  const int m0 = mt * 128, o0 = ot * 64;
  const int tid = threadIdx.x;
  const int w = tid >> 6, lane = tid & 63;
  const int fr = lane & 15;      // fragment row (A row / W row / C col)
  const int kc = lane >> 4;      // k-chunk (8 bf16)

  f32x4 acc[2][4];
#pragma unroll
  for (int i = 0; i < 2; ++i)
#pragma unroll
    for (int j = 0; j < 4; ++j)
#pragma unroll
      for (int r = 0; r < 4; ++r) acc[i][j][r] = 0.f;

  for (int k0 = 0; k0 < 512; k0 += 32) {
#pragma unroll
    for (int i = 0; i < 4; ++i) {
      int flat = tid + i * 256;        // 0..1023
      int r = flat >> 3, c4 = flat & 7;
      float4 av = *(const float4*)(A + (size_t)(m0 + r) * 512 + k0 + c4 * 4);
      ushort h0 = f2bf(av.x), h1 = f2bf(av.y), h2 = f2bf(av.z), h3 = f2bf(av.w);
      ushort l0 = f2bf(av.x - bf2f(h0)), l1 = f2bf(av.y - bf2f(h1));
      ushort l2 = f2bf(av.z - bf2f(h2)), l3 = f2bf(av.w - bf2f(h3));
      *(ushort4*)(&AsH[r][c4 * 4]) = make_ushort4(h0, h1, h2, h3);
      *(ushort4*)(&AsL[r][c4 * 4]) = make_ushort4(l0, l1, l2, l3);
    }
    __syncthreads();

    short8 ah[2], al[2], bh[4], bl[4];
#pragma unroll
    for (int i = 0; i < 2; ++i) {
      ah[i] = *(const short8*)(&AsH[w * 32 + i * 16 + fr][kc * 8]);
      al[i] = *(const short8*)(&AsL[w * 32 + i * 16 + fr][kc * 8]);
    }
#pragma unroll
    for (int j = 0; j < 4; ++j) {
      size_t off = (size_t)(o0 + j * 16 + fr) * 512 + k0 + kc * 8;
      bh[j] = *(const short8*)(Wh + off);
      bl[j] = *(const short8*)(Wl + off);
    }
#pragma unroll
    for (int i = 0; i < 2; ++i)
#pragma unroll
      for (int j = 0; j < 4; ++j) {
        acc[i][j] = __builtin_amdgcn_mfma_f32_16x16x32_bf16(ah[i], bh[j], acc[i][j], 0, 0, 0);
        acc[i][j] = __builtin_amdgcn_mfma_f32_16x16x32_bf16(ah[i], bl[j], acc[i][j], 0, 0, 0);
        acc[i][j] = __builtin_amdgcn_mfma_f32_16x16x32_bf16(al[i], bh[j], acc[i][j], 0, 0, 0);
        acc[i][j] = __builtin_amdgcn_mfma_f32_16x16x32_bf16(al[i], bl[j], acc[i][j], 0, 0, 0);
      }
    __syncthreads();
  }

#pragma unroll
  for (int i = 0; i < 2; ++i)
#pragma unroll
    for (int j = 0; j < 4; ++j)
#pragma unroll
      for (int r = 0; r < 4; ++r) {
        int m = m0 + w * 32 + i * 16 + (lane >> 4) * 4 + r;
        int o = o0 + j * 16 + fr;
        C[(size_t)m * 512 + o] = (acc[i][j][r] + bias[o]) * scale;
      }
}

// ---------------------------------------------------------------------------
// Transpose K into Kt[bh][e][n] for coalesced attention score reads.
// ---------------------------------------------------------------------------
__global__ __launch_bounds__(256) void transposeK_kernel(
    const float* __restrict__ K, float* __restrict__ Kt) {
  const int bh = blockIdx.x & 31;
  const int nt = blockIdx.x >> 5;       // 0..15
  const int b = bh >> 3, h = bh & 7;
  const int n0 = nt * 128;
  const int tid = threadIdx.x;
  __shared__ float T[128][65];

#pragma unroll
  for (int i = 0; i < 8; ++i) {
    int flat = tid + i * 256;           // 0..2047
    int r = flat >> 4;                  // 0..127
    int c4 = flat & 15;                 // 0..15
    float4 v = *(const float4*)(K + (((size_t)(n0 + r) * 4 + b) * 8 + h) * 64 + c4 * 4);
    T[r][c4 * 4 + 0] = v.x; T[r][c4 * 4 + 1] = v.y;
    T[r][c4 * 4 + 2] = v.z; T[r][c4 * 4 + 3] = v.w;
  }
  __syncthreads();

  const int nl = tid & 127;             // 0..127
  const int eg = tid >> 7;              // 0..1
#pragma unroll
  for (int e = eg * 32; e < eg * 32 + 32; ++e)
    Kt[((size_t)bh * 64 + e) * 2048 + n0 + nl] = T[nl][e];
}

// ---------------------------------------------------------------------------
// M scores, wave-cooperative gather. One wave per (bh, n).
// ---------------------------------------------------------------------------
__global__ __launch_bounds__(256) void mscore_kernel(
    const float* __restrict__ Q, const float* __restrict__ K,
    const int* __restrict__ idx, float* __restrict__ Mout) {
  const int bh = blockIdx.x & 31;
  const int c  = blockIdx.x >> 5;        // 0..511
  const int wv = threadIdx.x >> 6;       // 0..3
  const int lane = threadIdx.x & 63;
  const int n = c * 4 + wv;
  const int b = bh >> 3, h = bh & 7;
  const int g = lane >> 4;               // sample group 0..3
  const int e16 = lane & 15;             // element chunk within row

  const float4 qv = *(const float4*)(Q + (((size_t)n * 4 + b) * 8 + h) * 64 + e16 * 4);

  float mx = -INFINITY, sm = 0.f;
#pragma unroll
  for (int it = 0; it < 10; ++it) {
    const int s = it * 4 + g;
    const int kn = idx[n * UP + s];
    const float4 kv = *(const float4*)(K + (((size_t)kn * 4 + b) * 8 + h) * 64 + e16 * 4);
    float d = qv.x * kv.x + qv.y * kv.y + qv.z * kv.z + qv.w * kv.w;
    d += __shfl_xor(d, 1);
    d += __shfl_xor(d, 2);
    d += __shfl_xor(d, 4);
    d += __shfl_xor(d, 8);
    mx = fmaxf(mx, d);
    sm += d;
  }
  mx = fmaxf(mx, __shfl_xor(mx, 16));
  mx = fmaxf(mx, __shfl_xor(mx, 32));
  sm += __shfl_xor(sm, 16);
  sm += __shfl_xor(sm, 32);
  if (lane == 0) Mout[(size_t)bh * 2048 + n] = mx - sm * (1.0f / (float)KN);
}

// ---------------------------------------------------------------------------
// top-40 per (b,h) via 4-pass byte radix-select (R14, verified).
// ---------------------------------------------------------------------------
__global__ __launch_bounds__(256) void topk_kernel(
    const float* __restrict__ M, int* __restrict__ Mtop) {
  const int bh = blockIdx.x;
  __shared__ unsigned keys[2048];
  __shared__ int hist[256];
  __shared__ int suf[256];
  __shared__ int scal[2];
  __shared__ int ties[128];
  __shared__ int cnts[2];

  const int tid = threadIdx.x;
  const float* Mrow = M + (size_t)bh * 2048;
#pragma unroll
  for (int i = 0; i < 8; ++i) {
    int j = tid + i * 256;
    unsigned u = __float_as_uint(Mrow[j]);
    keys[j] = (u & 0x80000000u) ? ~u : (u | 0x80000000u);  // monotone map
  }
  if (tid < 2) cnts[tid] = 0;

  unsigned prefix = 0, prefmask = 0;
  int rank = UP;
#pragma unroll
  for (int shift = 24; shift >= 0; shift -= 8) {
    hist[tid] = 0;
    __syncthreads();
#pragma unroll
    for (int i = 0; i < 8; ++i) {
      unsigned k = keys[tid + i * 256];
      if ((k & prefmask) == prefix)
        atomicAdd(&hist[(k >> shift) & 0xFFu], 1);
    }
    __syncthreads();
    suf[tid] = hist[tid];
    __syncthreads();
#pragma unroll
    for (int off = 1; off < 256; off <<= 1) {
      int add = (tid + off < 256) ? suf[tid + off] : 0;
      __syncthreads();
      suf[tid] += add;
      __syncthreads();
    }
    {
      int above = suf[tid] - hist[tid];
      if (above < rank && rank <= suf[tid]) {
        scal[0] = tid;
        scal[1] = rank - above;
      }
    }
    __syncthreads();
    prefix |= ((unsigned)scal[0]) << shift;
    prefmask |= 0xFFu << shift;
    rank = scal[1];
    __syncthreads();
  }
  const unsigned T = prefix;

#pragma unroll
  for (int i = 0; i < 8; ++i) {
    int j = tid + i * 256;
    unsigned k = keys[j];
    if (k > T) {
      int p = atomicAdd(&cnts[0], 1);
      Mtop[bh * UP + p] = j;
    } else if (k == T) {
      int p = atomicAdd(&cnts[1], 1);
      if (p < 128) ties[p] = j;
    }
  }
  __syncthreads();
  if (tid == 0) {
    int base = cnts[0];
    int need = UP - base;
    int tc = cnts[1] < 128 ? cnts[1] : 128;
    for (int s = 0; s < need; ++s) {
      int best = 1 << 30, bj = 0;
      for (int j = 0; j < tc; ++j) {
        int v = ties[j];
        if (v < best) { best = v; bj = j; }
      }
      Mtop[bh * UP + base + s] = best;
      ties[bj] = 1 << 30;
    }
  }
}

// ---------------------------------------------------------------------------
// mean of V: two-phase coalesced column-sum (V is a [2048][2048] matrix).
// ---------------------------------------------------------------------------
__global__ __launch_bounds__(256) void meanv_part(
    const float* __restrict__ V, float* __restrict__ part) {
  const int rc = blockIdx.x >> 3;      // 0..31
  const int cc = blockIdx.x & 7;       // 0..7
  const int c = cc * 256 + threadIdx.x;
  const float* p = V + (size_t)rc * 64 * 2048 + c;
  float acc = 0.f;
#pragma unroll 8
  for (int i = 0; i < 64; ++i) acc += p[(size_t)i * 2048];
  part[(size_t)rc * 2048 + c] = acc;
}

__global__ __launch_bounds__(256) void meanv_final(
    const float* __restrict__ part, float* __restrict__ mnV) {
  const int c = blockIdx.x * 256 + threadIdx.x;   // 8 blocks
  float acc = 0.f;
#pragma unroll
  for (int r = 0; r < 32; ++r) acc += part[(size_t)r * 2048 + c];
  mnV[c] = acc * (1.0f / (float)KN);
}

// ---------------------------------------------------------------------------
// Selected-row machinery for the sparse output GEMM.
// ---------------------------------------------------------------------------
__global__ void selbuild_kernel(const int* __restrict__ Mtop,
                                int* __restrict__ flags) {
  const int i = blockIdx.x * 64 + threadIdx.x;   // 0..1279
  const int bh = i / UP;
  const int b = bh >> 3;
  flags[b * 2048 + Mtop[i]] = 1;
}

__global__ void selcompact_kernel(const int* __restrict__ flags,
                                  int* __restrict__ rows,
                                  int* __restrict__ cnt) {
  const int i = blockIdx.x * 256 + threadIdx.x;  // 0..8191
  if (flags[i]) {
    int p = atomicAdd(cnt, 1);
    rows[p] = i;                                  // flat row index b*2048+n
  }
}

// meanout[b][o] = dot(mnV[b*512..], Wo[o]) + bo[o]
__global__ __launch_bounds__(256) void meanout_kernel(
    const float* __restrict__ mnV, const float* __restrict__ Wo,
    const float* __restrict__ bo, float* __restrict__ mo) {
  const int b = blockIdx.x;           // 4 blocks
  for (int o = threadIdx.x; o < 512; o += 256) {
    const float* m = mnV + b * 512;
    const float* w = Wo + (size_t)o * 512;
    float acc = 0.f;
#pragma unroll 8
    for (int k = 0; k < 512; ++k) acc = fmaf(m[k], w[k], acc);
    mo[b * 512 + o] = acc + bo[o];
  }
}

// out broadcast fill (float4)
__global__ void fillout_kernel(const float* __restrict__ mo,
                               float* __restrict__ out) {
  size_t i = ((size_t)blockIdx.x * 256 + threadIdx.x) * 4;
  int d = (int)(i & 511);
  int b = (int)(i >> 20);
  float4 v = *(const float4*)(mo + (b << 9) + d);
  *(float4*)(out + i) = v;
}

// ---------------------------------------------------------------------------
// Sparse output GEMM over selected rows only (<=1280 of 8192).
// ---------------------------------------------------------------------------
__global__ __launch_bounds__(256) void gemm_rows(
    const float* __restrict__ ctx, const float* __restrict__ W,
    const float* __restrict__ bias, const int* __restrict__ rows,
    const int* __restrict__ cnt, float* __restrict__ out) {
  __shared__ float As[32][68];
  __shared__ float Ws[32][68];
  __shared__ int rsel[64];
  const int rt = blockIdx.x >> 3;      // 0..19
  const int ot = blockIdx.x & 7;       // 0..7
  const int o0 = ot * 64;
  const int tid = threadIdx.x;
  const int tx = tid & 15;
  const int ty = tid >> 4;
  const int n = *cnt;

  if (rt * 64 >= n) return;

  if (tid < 64) {
    int g = rt * 64 + tid;
    rsel[tid] = (g < n) ? rows[g] : rows[0];
  }
  __syncthreads();

  float acc[4][4] = {};
  for (int k0 = 0; k0 < 512; k0 += 32) {
#pragma unroll
    for (int i = 0; i < 2; ++i) {
      int flat = tid + i * 256;        // 0..511
      int r = flat >> 3;               // 0..63
      int c4 = flat & 7;
      float4 av = *(const float4*)(ctx + (size_t)rsel[r] * 512 + k0 + c4 * 4);
      float4 wv = *(const float4*)(W + (size_t)(o0 + r) * 512 + k0 + c4 * 4);
      As[c4 * 4 + 0][r] = av.x; As[c4 * 4 + 1][r] = av.y;
      As[c4 * 4 + 2][r] = av.z; As[c4 * 4 + 3][r] = av.w;
      Ws[c4 * 4 + 0][r] = wv.x; Ws[c4 * 4 + 1][r] = wv.y;
      Ws[c4 * 4 + 2][r] = wv.z; Ws[c4 * 4 + 3][r] = wv.w;
    }
    __syncthreads();
#pragma unroll
    for (int kk = 0; kk < 32; ++kk) {
      float a_[4], w_[4];
#pragma unroll
      for (int i = 0; i < 4; ++i) a_[i] = As[kk][ty * 4 + i];
#pragma unroll
      for (int j = 0; j < 4; ++j) w_[j] = Ws[kk][tx * 4 + j];
#pragma unroll
      for (int i = 0; i < 4; ++i)
#pragma unroll
        for (int j = 0; j < 4; ++j)
          acc[i][j] = fmaf(a_[i], w_[j], acc[i][j]);
    }
    __syncthreads();
  }

#pragma unroll
  for (int i = 0; i < 4; ++i) {
    int g = rt * 64 + ty * 4 + i;
    if (g < n) {
      int m = rsel[ty * 4 + i];
#pragma unroll
      for (int j = 0; j < 4; ++j) {
        int o = o0 + tx * 4 + j;
        out[(size_t)m * 512 + o] = acc[i][j] + bias[o];
      }
    }
  }
}

// ---------------------------------------------------------------------------
// Flash-split attention. Grid 1024: bid = (ch*8 + g)*32 + bh  (bid%8 == bh%8
// -> all 32 blocks of a bh on one XCD; 4 bh / XCD = 4MB working set).
// Block handles (bh, 5-query group g, n-chunk ch of 512).
// Emits per-chunk partials: chunk max, exp-sum, unnormalized PV.
// ---------------------------------------------------------------------------
#define QG 5   // queries per block
#define NC 4   // n-chunks
__global__ __launch_bounds__(256) void attn_part(
    const float* __restrict__ Q, const float* __restrict__ Kt,
    const float* __restrict__ V, const int* __restrict__ Mtop,
    float* __restrict__ pmax, float* __restrict__ psum,
    float* __restrict__ pvp) {
  const int bh = blockIdx.x & 31;
  const int t  = blockIdx.x >> 5;       // 0..31
  const int g  = t & 7;                 // query group
  const int ch = t >> 3;                // n-chunk
  const int b = bh >> 3, h = bh & 7;
  const int tid = threadIdx.x;
  const int wv = tid >> 6, lane = tid & 63;
  const int n0 = ch * 512;

  __shared__ float qs[QG][64];
  __shared__ float p[QG][512];
  __shared__ float redm[QG][4];
  __shared__ float reds[QG][4];
  __shared__ float pvs[4][QG][64];

  for (int i = tid; i < QG * 64; i += 256) {
    int q = i >> 6, e = i & 63;
    int nq = Mtop[bh * UP + g * QG + q];
    qs[q][e] = Q[(((size_t)nq * 4 + b) * 8 + h) * 64 + e];
  }
  __syncthreads();

  // scores: thread owns n = n0 + tid*2 + {0,1}
  const float* ktb = Kt + (size_t)bh * 64 * 2048;
  float d0[QG] = {}, d1[QG] = {};
  const int nb = n0 + tid * 2;
  for (int e = 0; e < 64; ++e) {
    float2 kv = *(const float2*)(ktb + (size_t)e * 2048 + nb);
#pragma unroll
    for (int q = 0; q < QG; ++q) {
      float qe = qs[q][e];
      d0[q] = fmaf(qe, kv.x, d0[q]);
      d1[q] = fmaf(qe, kv.y, d1[q]);
    }
  }

  // chunk max per q
#pragma unroll
  for (int q = 0; q < QG; ++q) {
    float m_ = fmaxf(d0[q], d1[q]);
#pragma unroll
    for (int off = 1; off < 64; off <<= 1)
      m_ = fmaxf(m_, __shfl_xor(m_, off));
    if (lane == 0) redm[q][wv] = m_;
  }
  __syncthreads();
  float gm[QG];
#pragma unroll
  for (int q = 0; q < QG; ++q)
    gm[q] = fmaxf(fmaxf(redm[q][0], redm[q][1]),
                  fmaxf(redm[q][2], redm[q][3]));

  // exp + chunk sum
  float ls[QG];
#pragma unroll
  for (int q = 0; q < QG; ++q) {
    float e0 = __expf(d0[q] - gm[q]);
    float e1 = __expf(d1[q] - gm[q]);
    p[q][tid * 2] = e0;
    p[q][tid * 2 + 1] = e1;
    ls[q] = e0 + e1;
  }
#pragma unroll
  for (int q = 0; q < QG; ++q) {
    float s_ = ls[q];
#pragma unroll
    for (int off = 1; off < 64; off <<= 1)
      s_ += __shfl_xor(s_, off);
    if (lane == 0) reds[q][wv] = s_;
  }
  __syncthreads();
  float den[QG];
#pragma unroll
  for (int q = 0; q < QG; ++q)
    den[q] = reds[q][0] + reds[q][1] + reds[q][2] + reds[q][3];

  // PV: wave wv handles nn in [wv*128, +128), lane = e (coalesced V rows)
  float acc[QG] = {};
  for (int nn = wv * 128; nn < wv * 128 + 128; ++nn) {
    float v = V[(((size_t)(n0 + nn) * 4 + b) * 8 + h) * 64 + lane];
#pragma unroll
    for (int q = 0; q < QG; ++q) acc[q] = fmaf(p[q][nn], v, acc[q]);
  }
#pragma unroll
  for (int q = 0; q < QG; ++q) pvs[wv][q][lane] = acc[q];
  __syncthreads();

  for (int i = tid; i < QG * 64; i += 256) {
    int q = i >> 6, e = i & 63;
    int slot = bh * UP + g * QG + q;
    float pv = pvs[0][q][e] + pvs[1][q][e] + pvs[2][q][e] + pvs[3][q][e];
    pvp[((size_t)slot * NC + ch) * 64 + e] = pv;
    if (e == 0) {
      pmax[slot * NC + ch] = gm[q];
      psum[slot * NC + ch] = den[q];
    }
  }
}

// combine NC chunk-partials per q-slot (flash rescale; exact up to rounding)
__global__ __launch_bounds__(64) void attn_combine(
    const float* __restrict__ pmax, const float* __restrict__ psum,
    const float* __restrict__ pvp, float* __restrict__ upd) {
  const int slot = blockIdx.x;     // 0..1279
  const int e = threadIdx.x;
  float m = -INFINITY;
#pragma unroll
  for (int ch = 0; ch < NC; ++ch) m = fmaxf(m, pmax[slot * NC + ch]);
  float den = 0.f, num = 0.f;
#pragma unroll
  for (int ch = 0; ch < NC; ++ch) {
    float w = __expf(pmax[slot * NC + ch] - m);
    den = fmaf(w, psum[slot * NC + ch], den);
    num = fmaf(w, pvp[((size_t)slot * NC + ch) * 64 + e], num);
  }
  upd[(size_t)slot * 64 + e] = num / den;
}

// ---------------------------------------------------------------------------
// ctx fill + scatter
// ---------------------------------------------------------------------------
__global__ void fillctx_kernel(const float* __restrict__ meanV,
                               float* __restrict__ ctx) {
  size_t i = ((size_t)blockIdx.x * 256 + threadIdx.x) * 4;
  int d = (int)(i & 511);
  int b = (int)(i >> 20);
  float4 v = *(const float4*)(meanV + (b << 9) + d);
  *(float4*)(ctx + i) = v;
}

__global__ void scatter_kernel(const float* __restrict__ upd,
                               const int* __restrict__ Mtop,
                               float* __restrict__ ctx) {
  const int blk = blockIdx.x;   // bh*40 + s
  const int bh = blk / UP;
  const int b = bh >> 3, h = bh & 7;
  const int n = Mtop[blk];
  ctx[((size_t)(b * 2048 + n)) * 512 + h * 64 + threadIdx.x] =
      upd[(size_t)blk * 64 + threadIdx.x];
}

// ---------------------------------------------------------------------------
// Workspace layout (~69.5 MiB used; ws >= 113 MiB proven in R4):
//   [0,       256K)    Mbuf   32*2048 f32
//   [256K,    576K)    upd    1280*64 f32
//   [589824,  598016)  mnV    32*64 f32
//   [598016,  603136)  Mtop   1280 i32
//   [634880,  897024)  vpart  32*2048 f32
//   [903168,  935936)  flags  8192 i32
//   [935936,  935940)  cnt    1 i32
//   [936192,  941312)  rows   1280 i32
//   [941312,  949504)  mo     4*512 f32
//   [1M, 17M) Q (ctx alias)   [17M, 33M) K   [33M, 49M) V   [49M, 65M) Kt
//   [65M..68M) Wh/Wl planes: 6 x 512 KiB (q,k,v)
//   [68M, 68M+32K) pmax   [68M+32K, 68M+64K) psum
//   [68M+64K, ~69.4M) pvp  1280*4*64 f32
// ---------------------------------------------------------------------------
extern "C" void kernel_launch(void* const* d_in, const int* in_sizes, int n_in,
                              void* d_out, int out_size, void* d_ws,
                              size_t ws_size, hipStream_t stream) {
  const float* query = (const float*)d_in[0];
  const float* key   = (const float*)d_in[1];
  const float* value = (const float*)d_in[2];
  const int*   idxs  = (const int*)d_in[3];
  const float* Wq = (const float*)d_in[4];
  const float* bq = (const float*)d_in[5];
  const float* Wk = (const float*)d_in[6];
  const float* bk = (const float*)d_in[7];
  const float* Wv = (const float*)d_in[8];
  const float* bv = (const float*)d_in[9];
  const float* Wo = (const float*)d_in[10];
  const float* bo = (const float*)d_in[11];
  float* out = (float*)d_out;    // reference output dtype is float32

  char* ws = (char*)d_ws;
  float*  Mbuf  = (float*)(ws + 0);
  float*  upd   = (float*)(ws + 262144);
  float*  mnV   = (float*)(ws + 589824);
  int*    Mtop  = (int*)  (ws + 598016);
  float*  vpart = (float*)(ws + 634880);
  int*    flags = (int*)  (ws + 903168);
  int*    cnt   = (int*)  (ws + 935936);
  int*    rows  = (int*)  (ws + 936192);
  float*  mo    = (float*)(ws + 941312);
  float*  Q     = (float*)(ws + MiB(1));
  float*  K     = (float*)(ws + MiB(17));
  float*  V     = (float*)(ws + MiB(33));
  float*  Kt    = (float*)(ws + MiB(49));
  ushort* Whq   = (ushort*)(ws + MiB(65));
  ushort* Wlq   = (ushort*)(ws + MiB(65) + 524288);
  ushort* Whk   = (ushort*)(ws + MiB(66));
  ushort* Wlk   = (ushort*)(ws + MiB(66) + 524288);
  ushort* Whv   = (ushort*)(ws + MiB(67));
  ushort* Wlv   = (ushort*)(ws + MiB(67) + 524288);
  float*  pmax  = (float*)(ws + MiB(68));
  float*  psum  = (float*)(ws + MiB(68) + 32768);
  float*  pvp   = (float*)(ws + MiB(68) + 65536);
  float*  ctx   = Q;   // Q dead after attn; ctx written afterwards

  // zero flags + cnt (contiguous region)
  hipMemsetAsync(flags, 0, 32768 + 4, stream);

  wsplit_kernel<<<512, 256, 0, stream>>>(Wq, Whq, Wlq);
  wsplit_kernel<<<512, 256, 0, stream>>>(Wk, Whk, Wlk);
  wsplit_kernel<<<512, 256, 0, stream>>>(Wv, Whv, Wlv);

  gemm_mfma<<<512, 256, 0, stream>>>(query, Whq, Wlq, bq, 0.125f, Q);
  gemm_mfma<<<512, 256, 0, stream>>>(key,   Whk, Wlk, bk, 1.0f,   K);
  gemm_mfma<<<512, 256, 0, stream>>>(value, Whv, Wlv, bv, 1.0f,   V);

  transposeK_kernel<<<512, 256, 0, stream>>>(K, Kt);

  mscore_kernel<<<16384, 256, 0, stream>>>(Q, K, idxs, Mbuf);
  topk_kernel<<<NBH, 256, 0, stream>>>(Mbuf, Mtop);
  selbuild_kernel<<<20, 64, 0, stream>>>(Mtop, flags);
  selcompact_kernel<<<32, 256, 0, stream>>>(flags, rows, cnt);

  meanv_part<<<256, 256, 0, stream>>>(V, vpart);
  meanv_final<<<8, 256, 0, stream>>>(vpart, mnV);

  attn_part<<<NBH * 32, 256, 0, stream>>>(Q, Kt, V, Mtop, pmax, psum, pvp);
  attn_combine<<<NBH * UP, 64, 0, stream>>>(pmax, psum, pvp, upd);

  fillctx_kernel<<<4096, 256, 0, stream>>>(mnV, ctx);
  scatter_kernel<<<NBH * UP, 64, 0, stream>>>(upd, Mtop, ctx);

  meanout_kernel<<<4, 256, 0, stream>>>(mnV, Wo, bo, mo);
  fillout_kernel<<<4096, 256, 0, stream>>>(mo, out);
  gemm_rows<<<160, 256, 0, stream>>>(ctx, Wo, bo, rows, cnt, out);
}